// Round 9
// baseline (635.754 us; speedup 1.0000x reference)
//
#include <hip/hip_runtime.h>

// ---------------------------------------------------------------------------
// GCN stack: 9 layers of  h = relu( Â (h W) + b ),  Â = D^-1/2 (A+I) D^-1/2
//   * Â(HW) == (ÂH)W  -> aggregate at width min(din,dout) per layer
//   * Â identical across layers -> CSR (self-loops folded) built once
// R23: extend R22's winning lever (fewer edge-list passes, wider contiguous
//     per-edge reads): 128-feat chunks for w256/w128 aggs -> 2 passes,
//     16-lane x uint4 groups (256B/edge/pass), per-edge shfl/weight/loop
//     cost halves again. w192 keeps the R22 64-feat kernel (192 % 128 != 0).
//     L2 slice 12.8MB (31% hit) accepted: instruction savings have beaten
//     hit-rate losses at every step (R15/R22 bracket). GEMM epilogue gets a
//     chunk-width mode (0=row, 1=chunk64, 2=chunk128; chunk128@Nc=128==row).
// ---------------------------------------------------------------------------

#define TPB 256

using bf16x8 = __attribute__((ext_vector_type(8))) __bf16;
using f32x4  = __attribute__((ext_vector_type(4))) float;
using f32x2  = __attribute__((ext_vector_type(2))) float;

__device__ __forceinline__ unsigned bf16rne(float x) {
    unsigned u = __float_as_uint(x);
    return (u + 0x7fffu + ((u >> 16) & 1u)) >> 16;
}

__device__ __forceinline__ f32x2 bl2(unsigned u) {
    return (f32x2){__uint_as_float(u << 16), __uint_as_float(u & 0xffff0000u)};
}

// async global->LDS, 16B per lane. l is the WAVE-UNIFORM base; HW adds lane*16.
__device__ __forceinline__ void stage16(const unsigned short* g, unsigned short* l) {
#if __has_builtin(__builtin_amdgcn_global_load_lds)
    __builtin_amdgcn_global_load_lds((const __attribute__((address_space(1))) void*)g,
                                     (__attribute__((address_space(3))) void*)l, 16, 0, 0);
#else
    *(uint4*)((char*)l + (threadIdx.x & 63) * 16) = *(const uint4*)g;
#endif
}

// ---------------- graph prep kernels ----------------

__global__ void zinit_kernel(int* cnt, int n) {
    int i = blockIdx.x * blockDim.x + threadIdx.x;
    if (i < n) cnt[i] = 0;
}

// counts AND captures per-edge rank within its dst (order irrelevant)
__global__ void count_kernel(const int* __restrict__ dst, int* __restrict__ cnt,
                             int* __restrict__ rank, int E) {
    int e = blockIdx.x * blockDim.x + threadIdx.x;
    if (e < E) rank[e] = atomicAdd(&cnt[dst[e]], 1);
}

// ---- contention-free counting sort (degree bins 0..63) ----

__global__ void blockhist_kernel(const int* __restrict__ cnt, int* __restrict__ localRank,
                                 int* __restrict__ hb, float* __restrict__ dinv,
                                 int n, int nb) {
    __shared__ int h[64];
    int t = threadIdx.x;
    if (t < 64) h[t] = 0;
    __syncthreads();
    int i = blockIdx.x * TPB + t;
    if (i < n) {
        int c = cnt[i];
        dinv[i] = rsqrtf((float)(c + 1));
        int d = c; if (d > 63) d = 63;
        localRank[i] = atomicAdd(&h[d], 1);      // LDS atomic: fast
    }
    __syncthreads();
    if (t < 64) hb[t * nb + blockIdx.x] = h[t];
}

__global__ __launch_bounds__(256) void sortscan_kernel(int* __restrict__ hb, int nb) {
    __shared__ int sh[64 * 256];                  // 64 KB, nb <= 256
    __shared__ int tot[64], base[64];
    int t = threadIdx.x;
    int total = 64 * nb;
    for (int i = t; i < total; i += 256) sh[i] = hb[i];
    __syncthreads();
    if (t < 64) {
        int run = 0;
        for (int b = 0; b < nb; b++) {
            int v = sh[t * nb + b];
            sh[t * nb + b] = run;
            run += v;
        }
        tot[t] = run;
    }
    __syncthreads();
    if (t == 0) {
        int acc = 0;
        for (int b = 0; b < 64; b++) { base[b] = acc; acc += tot[b]; }
    }
    __syncthreads();
    for (int i = t; i < total; i += 256) hb[i] = sh[i] + base[i / nb];
}

__global__ void scatter2_kernel(const int* __restrict__ cnt,
                                const int* __restrict__ localRank, const int* __restrict__ hb,
                                int* __restrict__ perm, int* __restrict__ pcnt,
                                int* __restrict__ iperm, int n, int nb) {
    int i = blockIdx.x * TPB + threadIdx.x;
    if (i >= n) return;
    int c = cnt[i];
    int d = c; if (d > 63) d = 63;
    int pos = hb[d * nb + blockIdx.x] + localRank[i];
    perm[pos] = i;
    pcnt[pos] = c;
    iperm[i] = pos;
}

__global__ void scan1_kernel(const int* __restrict__ pcnt, int* __restrict__ prowp2,
                             int* __restrict__ bsums, int n) {
    __shared__ int sh[TPB];
    int t = threadIdx.x;
    int i = blockIdx.x * TPB + t;
    int v = (i < n) ? (pcnt[i] + 1) : 0;
    sh[t] = v;
    __syncthreads();
    for (int off = 1; off < TPB; off <<= 1) {
        int x = (t >= off) ? sh[t - off] : 0;
        __syncthreads();
        sh[t] += x;
        __syncthreads();
    }
    if (i < n) prowp2[i] = sh[t] - v;
    if (t == TPB - 1) bsums[blockIdx.x] = sh[t];
}

__global__ void scan2_kernel(int* __restrict__ bsums, int nb) {
    __shared__ int sh[TPB];
    int t = threadIdx.x;
    int v = (t < nb) ? bsums[t] : 0;
    sh[t] = v;
    __syncthreads();
    for (int off = 1; off < TPB; off <<= 1) {
        int x = (t >= off) ? sh[t - off] : 0;
        __syncthreads();
        sh[t] += x;
        __syncthreads();
    }
    if (t < nb) bsums[t] = sh[t] - v;
}

__global__ void scan3_kernel(int* __restrict__ rowp, const int* __restrict__ bsums, int n) {
    int i = blockIdx.x * TPB + threadIdx.x;
    if (i < n) rowp[i] += bsums[blockIdx.x];
}

// rowo[orig] = CSR row start of orig node (one N-sized gather pass, not E)
__global__ void rowo_kernel(const int* __restrict__ iperm, const int* __restrict__ prowp2,
                            int* __restrict__ rowo, int n) {
    int i = blockIdx.x * TPB + threadIdx.x;
    if (i < n) rowo[i] = prowp2[iperm[i]];
}

// real + self edges written DIRECTLY into sorted dense CSR, atomic-free.
// edge = u16 src | bf16(weight) << 16   (N=50000 < 65536)
__global__ void fillself_kernel(const int* __restrict__ src, const int* __restrict__ dst,
                                const int* __restrict__ rank,
                                const float* __restrict__ dinv,
                                const int* __restrict__ rowo,
                                const int* __restrict__ cnt,
                                unsigned* __restrict__ edges2, int E, int n) {
    int id = blockIdx.x * blockDim.x + threadIdx.x;
    if (id < E) {
        int s = src[id], d = dst[id];
        int pos = rowo[d] + rank[id];
        edges2[pos] = (unsigned)s | (bf16rne(dinv[s] * dinv[d]) << 16);
    } else if (id < E + n) {
        int i = id - E;
        float dv = dinv[i];
        edges2[rowo[i] + cnt[i]] = (unsigned)i | (bf16rne(dv * dv) << 16);
    }
}

// ---------------- weight / input prep ----------------

struct WPtrs { const float* p[8]; };

__global__ void wt_all_kernel(WPtrs wp, unsigned short* __restrict__ Wts) {
    const int cum[9] = {0, 16384, 40960, 90112, 155648, 221184, 286720, 335872, 360448};
    const int Ns[8] = {128, 192, 256, 256, 256, 256, 192, 128};
    const int Ks[8] = {128, 128, 192, 256, 256, 256, 256, 192};
    int id = blockIdx.x * blockDim.x + threadIdx.x;
    if (id >= 360448) return;
    int L = 0;
#pragma unroll
    for (int t = 1; t < 8; t++) if (id >= cum[t]) L = t;
    int lid = id - cum[L];
    int N = Ns[L], K = Ks[L];
    int k = lid / N, n = lid - k * N;
    Wts[cum[L] + n * K + k] = (unsigned short)bf16rne(wp.p[L][lid]);
}

__global__ void cvt_bf16_kernel(const float* __restrict__ in, unsigned short* __restrict__ out,
                                int n4) {
    int i = blockIdx.x * blockDim.x + threadIdx.x;
    if (i >= n4) return;
    float4 v = ((const float4*)in)[i];
    uint2 o;
    o.x = bf16rne(v.x) | (bf16rne(v.y) << 16);
    o.y = bf16rne(v.z) | (bf16rne(v.w) << 16);
    ((uint2*)out)[i] = o;
}

// ---------------- MFMA GEMM (operand-swapped; outMode 0=row,1=c64,2=c128) ---

__global__ __launch_bounds__(256) void gemm_mfma_kernel(
    const unsigned short* __restrict__ A, const unsigned short* __restrict__ Wt,
    const float* __restrict__ bias, unsigned short* __restrict__ C,
    int M, int K, int Nc, int doBias, int doRelu, int outMode) {
    __shared__ unsigned short Qb[128 * 64];   // activations (nodes x K-chunk)
    __shared__ unsigned short Pb[128 * 64];   // weights (feats x K-chunk)
    int tid = threadIdx.x;
    int l = tid & 63, w = tid >> 6;
    int node0 = blockIdx.x * 128, feat0 = blockIdx.y * 128;

    f32x4 acc[4][4];
#pragma unroll
    for (int i = 0; i < 4; i++)
#pragma unroll
        for (int j = 0; j < 4; j++) acc[i][j] = (f32x4){0.f, 0.f, 0.f, 0.f};

    const unsigned short* gQ[4];
    const unsigned short* gP[4];
    unsigned short* lQ[4];
    unsigned short* lP[4];
#pragma unroll
    for (int h = 0; h < 4; h++) {
        int slot = tid + h * 256;
        int r = slot >> 3, q = slot & 7;
        int qg = q ^ (r & 7);                  // global-side swizzle
        int nd = node0 + r; if (nd > M - 1) nd = M - 1;
        int ft = feat0 + r; if (ft > Nc - 1) ft = Nc - 1;
        gQ[h] = A + (size_t)nd * K + qg * 8;
        gP[h] = Wt + (size_t)ft * K + qg * 8;
        lQ[h] = Qb + (size_t)(w * 64 + h * 256) * 8;
        lP[h] = Pb + (size_t)(w * 64 + h * 256) * 8;
    }

    int q4 = l >> 4, m16 = l & 15;
    int featHalf = w & 1, nodeHalf = w >> 1;
    int rP0 = featHalf * 64 + m16;
    int rQ0 = nodeHalf * 64 + m16;
    int sw = m16 & 7;

    for (int k0 = 0; k0 < K; k0 += 64) {
        __syncthreads();
#pragma unroll
        for (int h = 0; h < 4; h++) {
            stage16(gQ[h] + k0, lQ[h]);
            stage16(gP[h] + k0, lP[h]);
        }
        __syncthreads();
#pragma unroll
        for (int ko = 0; ko < 2; ko++) {
            bf16x8 pf[4], qf[4];
#pragma unroll
            for (int i = 0; i < 4; i++)
                pf[i] = *(const bf16x8*)(Pb + (rP0 + i * 16) * 64 + ((ko * 4 + q4) ^ sw) * 8);
#pragma unroll
            for (int j = 0; j < 4; j++)
                qf[j] = *(const bf16x8*)(Qb + (rQ0 + j * 16) * 64 + ((ko * 4 + q4) ^ sw) * 8);
#pragma unroll
            for (int i = 0; i < 4; i++)
#pragma unroll
                for (int j = 0; j < 4; j++)
                    acc[i][j] = __builtin_amdgcn_mfma_f32_16x16x32_bf16(pf[i], qf[j],
                                                                        acc[i][j], 0, 0, 0);
        }
    }

    // D layout: col(lane&15)=node, row(quad*4+reg)=feat -> 4 regs = 4 feats
#pragma unroll
    for (int i = 0; i < 4; i++) {
        int gf0 = feat0 + featHalf * 64 + i * 16 + q4 * 4;
        if (gf0 >= Nc) continue;
        float4 bv = make_float4(0.f, 0.f, 0.f, 0.f);
        if (doBias) bv = *(const float4*)(bias + gf0);
        size_t cb; int stride;
        if (outMode == 2) { cb = (size_t)(gf0 >> 7) * ((size_t)M * 128) + (gf0 & 127); stride = 128; }
        else if (outMode == 1) { cb = (size_t)(gf0 >> 6) * ((size_t)M * 64) + (gf0 & 63); stride = 64; }
        else { cb = (size_t)gf0; stride = Nc; }
#pragma unroll
        for (int j = 0; j < 4; j++) {
            int gn = node0 + nodeHalf * 64 + j * 16 + m16;
            if (gn >= M) continue;
            f32x4 v = acc[i][j];
            float x0 = v[0] + bv.x, x1 = v[1] + bv.y;
            float x2 = v[2] + bv.z, x3 = v[3] + bv.w;
            if (doRelu) {
                x0 = fmaxf(x0, 0.f); x1 = fmaxf(x1, 0.f);
                x2 = fmaxf(x2, 0.f); x3 = fmaxf(x3, 0.f);
            }
            uint2 o;
            o.x = bf16rne(x0) | (bf16rne(x1) << 16);
            o.y = bf16rne(x2) | (bf16rne(x3) << 16);
            size_t off = cb + (size_t)gn * stride;
            *(uint2*)(C + off) = o;
        }
    }
}

// out[m] = dot(A[m,0:128], w[0:128])  A bf16 row-major, one wave per row
__global__ void gemv128_bf16_kernel(const unsigned short* __restrict__ A,
                                    const float* __restrict__ w,
                                    float* __restrict__ out, int M) {
    int wid = (blockIdx.x * blockDim.x + threadIdx.x) >> 6;
    int lane = threadIdx.x & 63;
    if (wid >= M) return;
    const unsigned short* a = A + (size_t)wid * 128;
    float a0 = __uint_as_float((unsigned)a[lane] << 16);
    float a1 = __uint_as_float((unsigned)a[lane + 64] << 16);
    float s = a0 * w[lane] + a1 * w[lane + 64];
#pragma unroll
    for (int off = 32; off > 0; off >>= 1) s += __shfl_down(s, off);
    if (lane == 0) out[wid] = s;
}

// ---------------- aggregation: 64-feat chunks (w192 only) -------------------

// R22 kernel kept for width 192: 8 groups x 8 lanes, 128B/edge/pass,
// ping-pong A/B 4-edge sub-blocks, LPT.
__global__ __launch_bounds__(256) void agg_group_kernel(
    const uint4* __restrict__ in, const int* __restrict__ prowp2,
    const int* __restrict__ pcnt, const int* __restrict__ perm,
    const unsigned* __restrict__ edges2,
    const float* __restrict__ bias, uint4* __restrict__ out,
    int Q, int upx, int ngPerUnit, int NG, int n_nodes, int rowVec4,
    int doBias, int doRelu, int outChunked) {
    int xcd = blockIdx.x & 7;
    int slot = blockIdx.x >> 3;
    int u = slot / ngPerUnit;
    int ngIdx = slot - u * ngPerUnit;
    int unit = xcd * upx + u;
    int chunk = unit / Q;
    int q = unit - chunk * Q;
    int ng = ngIdx * Q + q;
    if (ng >= NG) return;
    ng = NG - 1 - ng;                          // heavy-degree blocks first (LPT)

    int wave = threadIdx.x >> 6;
    int lane = threadIdx.x & 63;
    int group = lane >> 3, fl = lane & 7;      // 8 groups x 8 lanes
    int gb = lane & ~7;
    int i = ng * 32 + wave * 8 + group;        // sorted index (32 nodes/block)
    if (i >= n_nodes) return;

    const uint4* sf = in + (size_t)chunk * n_nodes * 8 + fl;  // lane-fixed base
    int s0 = prowp2[i];
    int c = pcnt[i] + 1;
    int node = perm[i];
    const unsigned* ep = edges2 + s0;

    f32x2 acc[2][4];
#pragma unroll
    for (int k = 0; k < 2; k++)
#pragma unroll
        for (int m = 0; m < 4; m++) acc[k][m] = (f32x2){0.f, 0.f};

    unsigned ew = (fl < c) ? ep[fl] : 0u;
    unsigned eA[4]; uint4 pA[4];
#pragma unroll
    for (int j = 0; j < 4; j++) eA[j] = (unsigned)__shfl((int)ew, gb + j);
#pragma unroll
    for (int j = 0; j < 4; j++) pA[j] = sf[(size_t)(eA[j] & 0xffffu) * 8];

    for (int base = 0; base < c; base += 8) {
        unsigned ewn = (base + 8 + fl < c) ? ep[base + 8 + fl] : 0u;
        unsigned eB[4]; uint4 pB[4];
#pragma unroll
        for (int j = 0; j < 4; j++) eB[j] = (unsigned)__shfl((int)ew, gb + 4 + j);
#pragma unroll
        for (int j = 0; j < 4; j++) pB[j] = sf[(size_t)(eB[j] & 0xffffu) * 8];
#pragma unroll
        for (int j = 0; j < 4; j++) {
            float wgt = __uint_as_float(eA[j] & 0xffff0000u);
            f32x2 w2 = {wgt, wgt};
            int k = j & 1;
            acc[k][0] += w2 * bl2(pA[j].x);
            acc[k][1] += w2 * bl2(pA[j].y);
            acc[k][2] += w2 * bl2(pA[j].z);
            acc[k][3] += w2 * bl2(pA[j].w);
        }
#pragma unroll
        for (int j = 0; j < 4; j++) eA[j] = (unsigned)__shfl((int)ewn, gb + j);
#pragma unroll
        for (int j = 0; j < 4; j++) pA[j] = sf[(size_t)(eA[j] & 0xffffu) * 8];
#pragma unroll
        for (int j = 0; j < 4; j++) {
            float wgt = __uint_as_float(eB[j] & 0xffff0000u);
            f32x2 w2 = {wgt, wgt};
            int k = j & 1;
            acc[k][0] += w2 * bl2(pB[j].x);
            acc[k][1] += w2 * bl2(pB[j].y);
            acc[k][2] += w2 * bl2(pB[j].z);
            acc[k][3] += w2 * bl2(pB[j].w);
        }
        ew = ewn;
    }
    f32x2 s[4];
#pragma unroll
    for (int m = 0; m < 4; m++) s[m] = acc[0][m] + acc[1][m];

    if (doBias) {
        const float* bp = bias + chunk * 64 + fl * 8;
        float4 b0 = *(const float4*)bp;
        float4 b1 = *(const float4*)(bp + 4);
        s[0] += (f32x2){b0.x, b0.y};
        s[1] += (f32x2){b0.z, b0.w};
        s[2] += (f32x2){b1.x, b1.y};
        s[3] += (f32x2){b1.z, b1.w};
    }
    if (doRelu) {
#pragma unroll
        for (int m = 0; m < 4; m++) {
            s[m][0] = fmaxf(s[m][0], 0.f);
            s[m][1] = fmaxf(s[m][1], 0.f);
        }
    }
    uint4 o;
    o.x = bf16rne(s[0][0]) | (bf16rne(s[0][1]) << 16);
    o.y = bf16rne(s[1][0]) | (bf16rne(s[1][1]) << 16);
    o.z = bf16rne(s[2][0]) | (bf16rne(s[2][1]) << 16);
    o.w = bf16rne(s[3][0]) | (bf16rne(s[3][1]) << 16);
    size_t oi = outChunked ? ((size_t)chunk * n_nodes * 8 + (size_t)node * 8 + fl)
                           : ((size_t)node * rowVec4 + chunk * 8 + fl);
    out[oi] = o;
}

// ---------------- aggregation: 128-feat chunks (w256/w128) ------------------

// 4 groups x 16 lanes per wave, 16 nodes/block; each edge gathers 256B
// contiguous (16 lanes x uint4) -> per-edge shfl/weight/loop cost halves vs
// 64-feat. Edge words read in 16-wide windows; 4-edge sub-blocks pipelined
// ping-pong (issue sb+1 before FMA of sb). LPT order.
__global__ __launch_bounds__(256) void agg128_kernel(
    const uint4* __restrict__ in, const int* __restrict__ prowp2,
    const int* __restrict__ pcnt, const int* __restrict__ perm,
    const unsigned* __restrict__ edges2,
    const float* __restrict__ bias, uint4* __restrict__ out,
    int Q, int upx, int ngPerUnit, int NG, int n_nodes, int rowVec4,
    int doBias, int doRelu, int outChunked) {
    int xcd = blockIdx.x & 7;
    int slot = blockIdx.x >> 3;
    int u = slot / ngPerUnit;
    int ngIdx = slot - u * ngPerUnit;
    int unit = xcd * upx + u;
    int chunk = unit / Q;
    int q = unit - chunk * Q;
    int ng = ngIdx * Q + q;
    if (ng >= NG) return;
    ng = NG - 1 - ng;                          // heavy-degree blocks first (LPT)

    int wave = threadIdx.x >> 6;
    int lane = threadIdx.x & 63;
    int group = lane >> 4, fl = lane & 15;     // 4 groups x 16 lanes
    int gb = lane & ~15;
    int i = ng * 16 + wave * 4 + group;        // sorted index (16 nodes/block)
    if (i >= n_nodes) return;

    const uint4* sf = in + (size_t)chunk * n_nodes * 16 + fl;  // lane-fixed base
    int s0 = prowp2[i];
    int c = pcnt[i] + 1;
    int node = perm[i];
    const unsigned* ep = edges2 + s0;

    f32x2 acc[2][4];
#pragma unroll
    for (int k = 0; k < 2; k++)
#pragma unroll
        for (int m = 0; m < 4; m++) acc[k][m] = (f32x2){0.f, 0.f};

    // window 0 (edges 0..15); issue sub-block 0 gathers
    unsigned ew = (fl < c) ? ep[fl] : 0u;
    unsigned eA[4]; uint4 pA[4];
#pragma unroll
    for (int j = 0; j < 4; j++) eA[j] = (unsigned)__shfl((int)ew, gb + j);
#pragma unroll
    for (int j = 0; j < 4; j++) pA[j] = sf[(size_t)(eA[j] & 0xffffu) * 16];

    for (int base = 0; base < c; base += 16) {
        unsigned ewn = (base + 16 + fl < c) ? ep[base + 16 + fl] : 0u;  // next window
#pragma unroll
        for (int sb = 0; sb < 4; sb++) {
            unsigned esrc = (sb < 3) ? ew : ewn;
            int lsel = (sb + 1) & 3;
            unsigned eB[4]; uint4 pB[4];
#pragma unroll
            for (int j = 0; j < 4; j++)
                eB[j] = (unsigned)__shfl((int)esrc, gb + lsel * 4 + j);
#pragma unroll
            for (int j = 0; j < 4; j++) pB[j] = sf[(size_t)(eB[j] & 0xffffu) * 16];
            // FMA current sub-block (gathers issued one step ago)
#pragma unroll
            for (int j = 0; j < 4; j++) {
                float wgt = __uint_as_float(eA[j] & 0xffff0000u);  // inactive: +0.0
                f32x2 w2 = {wgt, wgt};
                int k = j & 1;
                acc[k][0] += w2 * bl2(pA[j].x);
                acc[k][1] += w2 * bl2(pA[j].y);
                acc[k][2] += w2 * bl2(pA[j].z);
                acc[k][3] += w2 * bl2(pA[j].w);
            }
#pragma unroll
            for (int j = 0; j < 4; j++) { eA[j] = eB[j]; pA[j] = pB[j]; }
        }
        ew = ewn;
    }
    f32x2 s[4];
#pragma unroll
    for (int m = 0; m < 4; m++) s[m] = acc[0][m] + acc[1][m];

    if (doBias) {
        const float* bp = bias + chunk * 128 + fl * 8;
        float4 b0 = *(const float4*)bp;
        float4 b1 = *(const float4*)(bp + 4);
        s[0] += (f32x2){b0.x, b0.y};
        s[1] += (f32x2){b0.z, b0.w};
        s[2] += (f32x2){b1.x, b1.y};
        s[3] += (f32x2){b1.z, b1.w};
    }
    if (doRelu) {
#pragma unroll
        for (int m = 0; m < 4; m++) {
            s[m][0] = fmaxf(s[m][0], 0.f);
            s[m][1] = fmaxf(s[m][1], 0.f);
        }
    }
    uint4 o;
    o.x = bf16rne(s[0][0]) | (bf16rne(s[0][1]) << 16);
    o.y = bf16rne(s[1][0]) | (bf16rne(s[1][1]) << 16);
    o.z = bf16rne(s[2][0]) | (bf16rne(s[2][1]) << 16);
    o.w = bf16rne(s[3][0]) | (bf16rne(s[3][1]) << 16);
    size_t oi = outChunked ? ((size_t)chunk * n_nodes * 16 + (size_t)node * 16 + fl)
                           : ((size_t)node * rowVec4 + chunk * 16 + fl);
    out[oi] = o;
}

// width-1 aggregation, fp32, sorted CSR: one thread per sorted node
__global__ void agg1_kernel(const float* __restrict__ in, const int* __restrict__ prowp2,
                            const int* __restrict__ pcnt, const int* __restrict__ perm,
                            const unsigned* __restrict__ edges2,
                            const float* __restrict__ bias, float* __restrict__ out,
                            int n_nodes) {
    int n = blockIdx.x * blockDim.x + threadIdx.x;
    if (n >= n_nodes) return;
    float acc = 0.f;
    int s0 = prowp2[n];
    int c = pcnt[n] + 1;
    for (int j = 0; j < c; j++) {
        unsigned e = edges2[s0 + j];
        acc += __uint_as_float(e & 0xffff0000u) * in[e & 0xffffu];
    }
    acc += bias[0];
    out[perm[n]] = acc;
}

// ---------------- host launcher ----------------

extern "C" void kernel_launch(void* const* d_in, const int* in_sizes, int n_in,
                              void* d_out, int out_size, void* d_ws, size_t ws_size,
                              hipStream_t stream) {
    const float* x = (const float*)d_in[0];
    const int* ei = (const int*)d_in[1];
    const int Nn = in_sizes[0] / 128;      // 50000
    const int E = in_sizes[1] / 2;         // 800000
    const int* src = ei;
    const int* dst = ei + E;

    char* ws = (char*)d_ws;
    size_t off = 0;
    auto alloc = [&](size_t bytes) -> char* {
        char* p = ws + off;
        off = (off + bytes + 255) & ~(size_t)255;
        return p;
    };
    int* cnt = (int*)alloc((size_t)Nn * 4);
    int* rank = (int*)alloc((size_t)E * 4);
    int* bsums = (int*)alloc(1024);
    float* dinv = (float*)alloc((size_t)Nn * 4);
    int* localRank = (int*)alloc((size_t)Nn * 4);
    int* hb = (int*)alloc((size_t)64 * 256 * 4);     // [64][nb], nb<=256
    int* perm = (int*)alloc((size_t)Nn * 4);
    int* pcnt = (int*)alloc((size_t)Nn * 4);
    int* iperm = (int*)alloc((size_t)Nn * 4);
    int* prowp2 = (int*)alloc((size_t)Nn * 4);
    int* rowo = (int*)alloc((size_t)Nn * 4);
    unsigned* edges2 = (unsigned*)alloc((size_t)(E + Nn + 64) * 4);
    unsigned short* T = (unsigned short*)alloc((size_t)Nn * 256 * 2);
    unsigned short* H = (unsigned short*)alloc((size_t)Nn * 256 * 2);
    unsigned short* Bx = (unsigned short*)alloc((size_t)Nn * 128 * 2);
    float* F = (float*)alloc((size_t)Nn * 4);
    unsigned short* Wts = (unsigned short*)alloc((size_t)400000 * 2);
    (void)ws_size;

    const int dims[9][2] = {{128,128},{128,192},{192,256},{256,256},{256,256},
                            {256,256},{256,192},{192,128},{128,1}};
    unsigned short* Wt[8];
    {
        size_t o = 0;
        for (int i = 0; i < 8; i++) { Wt[i] = Wts + o; o += (size_t)dims[i][0] * dims[i][1]; }
    }

    int nbN = (Nn + TPB - 1) / TPB;        // 196
    int nbE = (E + TPB - 1) / TPB;
    int nbEN = (E + Nn + TPB - 1) / TPB;

    // ---- graph prep: degree sort + direct sorted dense CSR build ----
    zinit_kernel<<<nbN, TPB, 0, stream>>>(cnt, Nn);
    count_kernel<<<nbE, TPB, 0, stream>>>(dst, cnt, rank, E);
    blockhist_kernel<<<nbN, TPB, 0, stream>>>(cnt, localRank, hb, dinv, Nn, nbN);
    sortscan_kernel<<<1, 256, 0, stream>>>(hb, nbN);
    scatter2_kernel<<<nbN, TPB, 0, stream>>>(cnt, localRank, hb, perm, pcnt, iperm,
                                             Nn, nbN);
    scan1_kernel<<<nbN, TPB, 0, stream>>>(pcnt, prowp2, bsums, Nn);
    scan2_kernel<<<1, TPB, 0, stream>>>(bsums, nbN);
    scan3_kernel<<<nbN, TPB, 0, stream>>>(prowp2, bsums, Nn);
    rowo_kernel<<<nbN, TPB, 0, stream>>>(iperm, prowp2, rowo, Nn);
    fillself_kernel<<<nbEN, TPB, 0, stream>>>(src, dst, rank, dinv, rowo, cnt,
                                              edges2, E, Nn);

    // ---- weight transpose (one dispatch) + input convert ----
    WPtrs wp;
    for (int i = 0; i < 8; i++) wp.p[i] = (const float*)d_in[2 + 2 * i];
    wt_all_kernel<<<(360448 + TPB - 1) / TPB, TPB, 0, stream>>>(wp, Wts);
    cvt_bf16_kernel<<<(Nn * 32 + TPB - 1) / TPB, TPB, 0, stream>>>(x, Bx, Nn * 32);

    auto gemm = [&](const unsigned short* A, int i, unsigned short* C, int K, int Nc,
                    int doBias, int doRelu, int outMode) {
        const float* b = (const float*)d_in[3 + 2 * i];
        dim3 grid((Nn + 127) / 128, (Nc + 127) / 128);   // x: nodes, y: feats
        gemm_mfma_kernel<<<grid, 256, 0, stream>>>(A, Wt[i], b, C, Nn, K, Nc,
                                                   doBias, doRelu, outMode);
    };
    int NG64 = (Nn + 31) / 32;             // 32 nodes/block (64-feat kernel)
    int NG128 = (Nn + 15) / 16;            // 16 nodes/block (128-feat kernel)
    auto agg = [&](const unsigned short* inb, unsigned short* outb, int w, int i,
                   int doBias, int doRelu, int outChunked) {
        const float* b = (const float*)d_in[3 + 2 * i];
        if (w == 192) {
            int Q = 8, upx = 3;                           // nch=3
            int ngPerUnit = (NG64 + Q - 1) / Q;
            agg_group_kernel<<<upx * ngPerUnit * 8, 256, 0, stream>>>(
                (const uint4*)inb, prowp2, pcnt, perm, edges2, b, (uint4*)outb,
                Q, upx, ngPerUnit, NG64, Nn, w / 8, doBias, doRelu, outChunked);
        } else {
            int nch = w / 128;                            // 1 or 2
            int Q = (nch == 2) ? 4 : 8;
            int upx = nch * Q / 8;                        // 1
            int ngPerUnit = (NG128 + Q - 1) / Q;
            agg128_kernel<<<upx * ngPerUnit * 8, 256, 0, stream>>>(
                (const uint4*)inb, prowp2, pcnt, perm, edges2, b, (uint4*)outb,
                Q, upx, ngPerUnit, NG128, Nn, w / 8, doBias, doRelu, outChunked);
        }
    };

    // layout chain: GEMM outMode 2=chunk128 (==row at Nc=128), 1=chunk64, 0=row
    gemm(Bx, 0, T, 128, 128, 0, 0, 2);      // G0: t = x@W0          -> T row/c128
    agg(T, H, 128, 0, 1, 1, 0);             // A0: h1 = At+b0 relu   -> H row
    agg(H, T, 128, 1, 0, 0, 0);             // A1: u = A h1          -> T row
    gemm(T, 1, H, 128, 192, 1, 1, 1);       // G1: h2 = u@W1+b1 relu -> H c64
    agg(H, T, 192, 2, 0, 0, 0);             // A2: u = A h2          -> T row
    gemm(T, 2, H, 192, 256, 1, 1, 0);       // G2: h3 = u@W2+b2 relu -> H row
    gemm(H, 3, T, 256, 256, 0, 0, 2);       // G3: t = h3@W3         -> T c128
    agg(T, H, 256, 3, 1, 1, 0);             // A3: h4 = At+b3 relu   -> H row
    gemm(H, 4, T, 256, 256, 0, 0, 2);       // G4: t = h4@W4         -> T c128
    agg(T, H, 256, 4, 1, 0, 0);             // A4: h5 = At+b4        -> H row
    gemm(H, 5, T, 256, 256, 0, 0, 2);       // G5: t = h5@W5         -> T c128
    agg(T, H, 256, 5, 1, 1, 0);             // A5: h6 = At+b5 relu   -> H row
    gemm(H, 6, T, 256, 192, 0, 0, 1);       // G6: t = h6@W6         -> T c64
    agg(T, H, 192, 6, 1, 1, 0);             // A6: h7 = At+b6 relu   -> H row
    gemm(H, 7, T, 192, 128, 0, 0, 2);       // G7: t = h7@W7         -> T row/c128
    agg(T, H, 128, 7, 1, 1, 0);             // A7: h8 = At+b7 relu   -> H row
    gemv128_bf16_kernel<<<(Nn + 3) / 4, 256, 0, stream>>>(H, (const float*)d_in[2 + 16],
                                                          F, Nn);
    agg1_kernel<<<nbN, TPB, 0, stream>>>(F, prowp2, pcnt, perm, edges2,
                                         (const float*)d_in[3 + 16], (float*)d_out, Nn);
}

// Round 10
// 578.552 us; speedup vs baseline: 1.0989x; 1.0989x over previous
//
#include <hip/hip_runtime.h>

// ---------------------------------------------------------------------------
// GCN stack: 9 layers of  h = relu( Â (h W) + b ),  Â = D^-1/2 (A+I) D^-1/2
//   * Â(HW) == (ÂH)W  -> aggregate at width min(din,dout) per layer
//   * Â identical across layers -> CSR (self-loops folded) built once
// R24: REVERT R23's 128-feat agg (hit pre-declared failure: w256 agg 49.9us,
//     FETCH 156MB -- 12.8MB slice thrashes 4MB L2; LLC-latency gathers beat
//     the instruction savings). Working-set trade now mapped: R15(25.6MB,
//     lose) / R23(12.8MB, lose) / R22(6.4MB, WIN) / R14(3.2MB, slower) ->
//     64-feat chunks are the optimum. Back to R22 agg everywhere.
//     Prep-chain: fuse wt_all+cvt_bf16 (one dispatch); fold scan2 into
//     scan3 (each block reduces bsums[0..bid) itself) -- 2 fewer launches.
// ---------------------------------------------------------------------------

#define TPB 256

using bf16x8 = __attribute__((ext_vector_type(8))) __bf16;
using f32x4  = __attribute__((ext_vector_type(4))) float;
using f32x2  = __attribute__((ext_vector_type(2))) float;

__device__ __forceinline__ unsigned bf16rne(float x) {
    unsigned u = __float_as_uint(x);
    return (u + 0x7fffu + ((u >> 16) & 1u)) >> 16;
}

__device__ __forceinline__ f32x2 bl2(unsigned u) {
    return (f32x2){__uint_as_float(u << 16), __uint_as_float(u & 0xffff0000u)};
}

// async global->LDS, 16B per lane. l is the WAVE-UNIFORM base; HW adds lane*16.
__device__ __forceinline__ void stage16(const unsigned short* g, unsigned short* l) {
#if __has_builtin(__builtin_amdgcn_global_load_lds)
    __builtin_amdgcn_global_load_lds((const __attribute__((address_space(1))) void*)g,
                                     (__attribute__((address_space(3))) void*)l, 16, 0, 0);
#else
    *(uint4*)((char*)l + (threadIdx.x & 63) * 16) = *(const uint4*)g;
#endif
}

// ---------------- graph prep kernels ----------------

__global__ void zinit_kernel(int* cnt, int n) {
    int i = blockIdx.x * blockDim.x + threadIdx.x;
    if (i < n) cnt[i] = 0;
}

// counts AND captures per-edge rank within its dst (order irrelevant)
__global__ void count_kernel(const int* __restrict__ dst, int* __restrict__ cnt,
                             int* __restrict__ rank, int E) {
    int e = blockIdx.x * blockDim.x + threadIdx.x;
    if (e < E) rank[e] = atomicAdd(&cnt[dst[e]], 1);
}

// ---- contention-free counting sort (degree bins 0..63) ----

__global__ void blockhist_kernel(const int* __restrict__ cnt, int* __restrict__ localRank,
                                 int* __restrict__ hb, float* __restrict__ dinv,
                                 int n, int nb) {
    __shared__ int h[64];
    int t = threadIdx.x;
    if (t < 64) h[t] = 0;
    __syncthreads();
    int i = blockIdx.x * TPB + t;
    if (i < n) {
        int c = cnt[i];
        dinv[i] = rsqrtf((float)(c + 1));
        int d = c; if (d > 63) d = 63;
        localRank[i] = atomicAdd(&h[d], 1);      // LDS atomic: fast
    }
    __syncthreads();
    if (t < 64) hb[t * nb + blockIdx.x] = h[t];
}

__global__ __launch_bounds__(256) void sortscan_kernel(int* __restrict__ hb, int nb) {
    __shared__ int sh[64 * 256];                  // 64 KB, nb <= 256
    __shared__ int tot[64], base[64];
    int t = threadIdx.x;
    int total = 64 * nb;
    for (int i = t; i < total; i += 256) sh[i] = hb[i];
    __syncthreads();
    if (t < 64) {
        int run = 0;
        for (int b = 0; b < nb; b++) {
            int v = sh[t * nb + b];
            sh[t * nb + b] = run;
            run += v;
        }
        tot[t] = run;
    }
    __syncthreads();
    if (t == 0) {
        int acc = 0;
        for (int b = 0; b < 64; b++) { base[b] = acc; acc += tot[b]; }
    }
    __syncthreads();
    for (int i = t; i < total; i += 256) hb[i] = sh[i] + base[i / nb];
}

__global__ void scatter2_kernel(const int* __restrict__ cnt,
                                const int* __restrict__ localRank, const int* __restrict__ hb,
                                int* __restrict__ perm, int* __restrict__ pcnt,
                                int* __restrict__ iperm, int n, int nb) {
    int i = blockIdx.x * TPB + threadIdx.x;
    if (i >= n) return;
    int c = cnt[i];
    int d = c; if (d > 63) d = 63;
    int pos = hb[d * nb + blockIdx.x] + localRank[i];
    perm[pos] = i;
    pcnt[pos] = c;
    iperm[i] = pos;
}

__global__ void scan1_kernel(const int* __restrict__ pcnt, int* __restrict__ prowp2,
                             int* __restrict__ bsums, int n) {
    __shared__ int sh[TPB];
    int t = threadIdx.x;
    int i = blockIdx.x * TPB + t;
    int v = (i < n) ? (pcnt[i] + 1) : 0;
    sh[t] = v;
    __syncthreads();
    for (int off = 1; off < TPB; off <<= 1) {
        int x = (t >= off) ? sh[t - off] : 0;
        __syncthreads();
        sh[t] += x;
        __syncthreads();
    }
    if (i < n) prowp2[i] = sh[t] - v;
    if (t == TPB - 1) bsums[blockIdx.x] = sh[t];
}

// scan3 with scan2 folded in: each block reduces bsums[0..blockIdx.x) itself.
__global__ void scan3_kernel(int* __restrict__ rowp, const int* __restrict__ bsums,
                             int n, int nb) {
    __shared__ int sh[TPB];
    int t = threadIdx.x;
    int v = (t < nb && t < (int)blockIdx.x) ? bsums[t] : 0;
    sh[t] = v;
    __syncthreads();
    for (int off = 1; off < TPB; off <<= 1) {
        int x = (t >= off) ? sh[t - off] : 0;
        __syncthreads();
        sh[t] += x;
        __syncthreads();
    }
    int offset = sh[TPB - 1];                     // sum of bsums[0..bid)
    int i = blockIdx.x * TPB + t;
    if (i < n) rowp[i] += offset;
}

// rowo[orig] = CSR row start of orig node (one N-sized gather pass, not E)
__global__ void rowo_kernel(const int* __restrict__ iperm, const int* __restrict__ prowp2,
                            int* __restrict__ rowo, int n) {
    int i = blockIdx.x * TPB + threadIdx.x;
    if (i < n) rowo[i] = prowp2[iperm[i]];
}

// real + self edges written DIRECTLY into sorted dense CSR, atomic-free.
// edge = u16 src | bf16(weight) << 16   (N=50000 < 65536)
__global__ void fillself_kernel(const int* __restrict__ src, const int* __restrict__ dst,
                                const int* __restrict__ rank,
                                const float* __restrict__ dinv,
                                const int* __restrict__ rowo,
                                const int* __restrict__ cnt,
                                unsigned* __restrict__ edges2, int E, int n) {
    int id = blockIdx.x * blockDim.x + threadIdx.x;
    if (id < E) {
        int s = src[id], d = dst[id];
        int pos = rowo[d] + rank[id];
        edges2[pos] = (unsigned)s | (bf16rne(dinv[s] * dinv[d]) << 16);
    } else if (id < E + n) {
        int i = id - E;
        float dv = dinv[i];
        edges2[rowo[i] + cnt[i]] = (unsigned)i | (bf16rne(dv * dv) << 16);
    }
}

// ---------------- weight / input prep (fused, one dispatch) ----------------

struct WPtrs { const float* p[8]; };

__global__ void wtcvt_kernel(WPtrs wp, unsigned short* __restrict__ Wts,
                             const float* __restrict__ xin,
                             unsigned short* __restrict__ Bx, int n4) {
    const int cum[9] = {0, 16384, 40960, 90112, 155648, 221184, 286720, 335872, 360448};
    const int Ns[8] = {128, 192, 256, 256, 256, 256, 192, 128};
    const int Ks[8] = {128, 128, 192, 256, 256, 256, 256, 192};
    int id = blockIdx.x * blockDim.x + threadIdx.x;
    if (id < 360448) {
        int L = 0;
#pragma unroll
        for (int t = 1; t < 8; t++) if (id >= cum[t]) L = t;
        int lid = id - cum[L];
        int N = Ns[L], K = Ks[L];
        int k = lid / N, n = lid - k * N;
        Wts[cum[L] + n * K + k] = (unsigned short)bf16rne(wp.p[L][lid]);
    } else {
        int i = id - 360448;
        if (i >= n4) return;
        float4 v = ((const float4*)xin)[i];
        uint2 o;
        o.x = bf16rne(v.x) | (bf16rne(v.y) << 16);
        o.y = bf16rne(v.z) | (bf16rne(v.w) << 16);
        ((uint2*)Bx)[i] = o;
    }
}

// ---------------- MFMA GEMM (operand-swapped; chunked-out = 64-feat) --------

__global__ __launch_bounds__(256) void gemm_mfma_kernel(
    const unsigned short* __restrict__ A, const unsigned short* __restrict__ Wt,
    const float* __restrict__ bias, unsigned short* __restrict__ C,
    int M, int K, int Nc, int doBias, int doRelu, int outChunked) {
    __shared__ unsigned short Qb[128 * 64];   // activations (nodes x K-chunk)
    __shared__ unsigned short Pb[128 * 64];   // weights (feats x K-chunk)
    int tid = threadIdx.x;
    int l = tid & 63, w = tid >> 6;
    int node0 = blockIdx.x * 128, feat0 = blockIdx.y * 128;

    f32x4 acc[4][4];
#pragma unroll
    for (int i = 0; i < 4; i++)
#pragma unroll
        for (int j = 0; j < 4; j++) acc[i][j] = (f32x4){0.f, 0.f, 0.f, 0.f};

    const unsigned short* gQ[4];
    const unsigned short* gP[4];
    unsigned short* lQ[4];
    unsigned short* lP[4];
#pragma unroll
    for (int h = 0; h < 4; h++) {
        int slot = tid + h * 256;
        int r = slot >> 3, q = slot & 7;
        int qg = q ^ (r & 7);                  // global-side swizzle
        int nd = node0 + r; if (nd > M - 1) nd = M - 1;
        int ft = feat0 + r; if (ft > Nc - 1) ft = Nc - 1;
        gQ[h] = A + (size_t)nd * K + qg * 8;
        gP[h] = Wt + (size_t)ft * K + qg * 8;
        lQ[h] = Qb + (size_t)(w * 64 + h * 256) * 8;
        lP[h] = Pb + (size_t)(w * 64 + h * 256) * 8;
    }

    int q4 = l >> 4, m16 = l & 15;
    int featHalf = w & 1, nodeHalf = w >> 1;
    int rP0 = featHalf * 64 + m16;
    int rQ0 = nodeHalf * 64 + m16;
    int sw = m16 & 7;

    for (int k0 = 0; k0 < K; k0 += 64) {
        __syncthreads();
#pragma unroll
        for (int h = 0; h < 4; h++) {
            stage16(gQ[h] + k0, lQ[h]);
            stage16(gP[h] + k0, lP[h]);
        }
        __syncthreads();
#pragma unroll
        for (int ko = 0; ko < 2; ko++) {
            bf16x8 pf[4], qf[4];
#pragma unroll
            for (int i = 0; i < 4; i++)
                pf[i] = *(const bf16x8*)(Pb + (rP0 + i * 16) * 64 + ((ko * 4 + q4) ^ sw) * 8);
#pragma unroll
            for (int j = 0; j < 4; j++)
                qf[j] = *(const bf16x8*)(Qb + (rQ0 + j * 16) * 64 + ((ko * 4 + q4) ^ sw) * 8);
#pragma unroll
            for (int i = 0; i < 4; i++)
#pragma unroll
                for (int j = 0; j < 4; j++)
                    acc[i][j] = __builtin_amdgcn_mfma_f32_16x16x32_bf16(pf[i], qf[j],
                                                                        acc[i][j], 0, 0, 0);
        }
    }

    // D layout: col(lane&15)=node, row(quad*4+reg)=feat -> 4 regs = 4 feats
#pragma unroll
    for (int i = 0; i < 4; i++) {
        int gf0 = feat0 + featHalf * 64 + i * 16 + q4 * 4;
        if (gf0 >= Nc) continue;
        float4 bv = make_float4(0.f, 0.f, 0.f, 0.f);
        if (doBias) bv = *(const float4*)(bias + gf0);
        size_t cb = outChunked ? ((size_t)(gf0 >> 6) * ((size_t)M * 64) + (gf0 & 63))
                               : (size_t)gf0;
#pragma unroll
        for (int j = 0; j < 4; j++) {
            int gn = node0 + nodeHalf * 64 + j * 16 + m16;
            if (gn >= M) continue;
            f32x4 v = acc[i][j];
            float x0 = v[0] + bv.x, x1 = v[1] + bv.y;
            float x2 = v[2] + bv.z, x3 = v[3] + bv.w;
            if (doRelu) {
                x0 = fmaxf(x0, 0.f); x1 = fmaxf(x1, 0.f);
                x2 = fmaxf(x2, 0.f); x3 = fmaxf(x3, 0.f);
            }
            uint2 o;
            o.x = bf16rne(x0) | (bf16rne(x1) << 16);
            o.y = bf16rne(x2) | (bf16rne(x3) << 16);
            size_t off = outChunked ? (cb + (size_t)gn * 64) : (cb + (size_t)gn * Nc);
            *(uint2*)(C + off) = o;
        }
    }
}

// out[m] = dot(A[m,0:128], w[0:128])  A bf16 row-major, one wave per row
__global__ void gemv128_bf16_kernel(const unsigned short* __restrict__ A,
                                    const float* __restrict__ w,
                                    float* __restrict__ out, int M) {
    int wid = (blockIdx.x * blockDim.x + threadIdx.x) >> 6;
    int lane = threadIdx.x & 63;
    if (wid >= M) return;
    const unsigned short* a = A + (size_t)wid * 128;
    float a0 = __uint_as_float((unsigned)a[lane] << 16);
    float a1 = __uint_as_float((unsigned)a[lane + 64] << 16);
    float s = a0 * w[lane] + a1 * w[lane + 64];
#pragma unroll
    for (int off = 32; off > 0; off >>= 1) s += __shfl_down(s, off);
    if (lane == 0) out[wid] = s;
}

// ---------------- aggregation: 64-feat chunks, 8-lane groups, pipelined -----

// R22 measured-best: 8 groups x 8 lanes per wave, one node per group,
// 32 nodes/block; each edge gathers 128B contiguous (8 lanes x uint4).
// Ping-pong A/B 4-edge sub-blocks: gathers for k+1 issued before FMA of k;
// edge words loaded 8 at a time. LPT order. Chunk->XCD slices (6.4MB).
__global__ __launch_bounds__(256) void agg_group_kernel(
    const uint4* __restrict__ in, const int* __restrict__ prowp2,
    const int* __restrict__ pcnt, const int* __restrict__ perm,
    const unsigned* __restrict__ edges2,
    const float* __restrict__ bias, uint4* __restrict__ out,
    int Q, int upx, int ngPerUnit, int NG, int n_nodes, int rowVec4,
    int doBias, int doRelu, int outChunked) {
    int xcd = blockIdx.x & 7;
    int slot = blockIdx.x >> 3;
    int u = slot / ngPerUnit;
    int ngIdx = slot - u * ngPerUnit;
    int unit = xcd * upx + u;
    int chunk = unit / Q;
    int q = unit - chunk * Q;
    int ng = ngIdx * Q + q;
    if (ng >= NG) return;
    ng = NG - 1 - ng;                          // heavy-degree blocks first (LPT)

    int wave = threadIdx.x >> 6;
    int lane = threadIdx.x & 63;
    int group = lane >> 3, fl = lane & 7;      // 8 groups x 8 lanes
    int gb = lane & ~7;
    int i = ng * 32 + wave * 8 + group;        // sorted index (32 nodes/block)
    if (i >= n_nodes) return;

    const uint4* sf = in + (size_t)chunk * n_nodes * 8 + fl;  // lane-fixed base
    int s0 = prowp2[i];
    int c = pcnt[i] + 1;
    int node = perm[i];
    const unsigned* ep = edges2 + s0;

    f32x2 acc[2][4];
#pragma unroll
    for (int k = 0; k < 2; k++)
#pragma unroll
        for (int m = 0; m < 4; m++) acc[k][m] = (f32x2){0.f, 0.f};

    // prologue: ew covers edges 0..7 (sub-blocks 0,1); issue block 0 gathers
    unsigned ew = (fl < c) ? ep[fl] : 0u;
    unsigned eA[4]; uint4 pA[4];
#pragma unroll
    for (int j = 0; j < 4; j++) eA[j] = (unsigned)__shfl((int)ew, gb + j);
#pragma unroll
    for (int j = 0; j < 4; j++) pA[j] = sf[(size_t)(eA[j] & 0xffffu) * 8];

    for (int base = 0; base < c; base += 8) {
        unsigned ewn = (base + 8 + fl < c) ? ep[base + 8 + fl] : 0u;  // blocks k+2,k+3
        unsigned eB[4]; uint4 pB[4];
#pragma unroll
        for (int j = 0; j < 4; j++) eB[j] = (unsigned)__shfl((int)ew, gb + 4 + j);
#pragma unroll
        for (int j = 0; j < 4; j++) pB[j] = sf[(size_t)(eB[j] & 0xffffu) * 8];
        // FMA block k (pA issued one half-iter ago)
#pragma unroll
        for (int j = 0; j < 4; j++) {
            float wgt = __uint_as_float(eA[j] & 0xffff0000u);         // inactive: +0.0
            f32x2 w2 = {wgt, wgt};
            int k = j & 1;
            acc[k][0] += w2 * bl2(pA[j].x);
            acc[k][1] += w2 * bl2(pA[j].y);
            acc[k][2] += w2 * bl2(pA[j].z);
            acc[k][3] += w2 * bl2(pA[j].w);
        }
        // issue block k+2 gathers
#pragma unroll
        for (int j = 0; j < 4; j++) eA[j] = (unsigned)__shfl((int)ewn, gb + j);
#pragma unroll
        for (int j = 0; j < 4; j++) pA[j] = sf[(size_t)(eA[j] & 0xffffu) * 8];
        // FMA block k+1
#pragma unroll
        for (int j = 0; j < 4; j++) {
            float wgt = __uint_as_float(eB[j] & 0xffff0000u);
            f32x2 w2 = {wgt, wgt};
            int k = j & 1;
            acc[k][0] += w2 * bl2(pB[j].x);
            acc[k][1] += w2 * bl2(pB[j].y);
            acc[k][2] += w2 * bl2(pB[j].z);
            acc[k][3] += w2 * bl2(pB[j].w);
        }
        ew = ewn;
    }
    f32x2 s[4];
#pragma unroll
    for (int m = 0; m < 4; m++) s[m] = acc[0][m] + acc[1][m];

    if (doBias) {
        const float* bp = bias + chunk * 64 + fl * 8;
        float4 b0 = *(const float4*)bp;
        float4 b1 = *(const float4*)(bp + 4);
        s[0] += (f32x2){b0.x, b0.y};
        s[1] += (f32x2){b0.z, b0.w};
        s[2] += (f32x2){b1.x, b1.y};
        s[3] += (f32x2){b1.z, b1.w};
    }
    if (doRelu) {
#pragma unroll
        for (int m = 0; m < 4; m++) {
            s[m][0] = fmaxf(s[m][0], 0.f);
            s[m][1] = fmaxf(s[m][1], 0.f);
        }
    }
    uint4 o;
    o.x = bf16rne(s[0][0]) | (bf16rne(s[0][1]) << 16);
    o.y = bf16rne(s[1][0]) | (bf16rne(s[1][1]) << 16);
    o.z = bf16rne(s[2][0]) | (bf16rne(s[2][1]) << 16);
    o.w = bf16rne(s[3][0]) | (bf16rne(s[3][1]) << 16);
    size_t oi = outChunked ? ((size_t)chunk * n_nodes * 8 + (size_t)node * 8 + fl)
                           : ((size_t)node * rowVec4 + chunk * 8 + fl);
    out[oi] = o;
}

// width-1 aggregation, fp32, sorted CSR: one thread per sorted node
__global__ void agg1_kernel(const float* __restrict__ in, const int* __restrict__ prowp2,
                            const int* __restrict__ pcnt, const int* __restrict__ perm,
                            const unsigned* __restrict__ edges2,
                            const float* __restrict__ bias, float* __restrict__ out,
                            int n_nodes) {
    int n = blockIdx.x * blockDim.x + threadIdx.x;
    if (n >= n_nodes) return;
    float acc = 0.f;
    int s0 = prowp2[n];
    int c = pcnt[n] + 1;
    for (int j = 0; j < c; j++) {
        unsigned e = edges2[s0 + j];
        acc += __uint_as_float(e & 0xffff0000u) * in[e & 0xffffu];
    }
    acc += bias[0];
    out[perm[n]] = acc;
}

// ---------------- host launcher ----------------

extern "C" void kernel_launch(void* const* d_in, const int* in_sizes, int n_in,
                              void* d_out, int out_size, void* d_ws, size_t ws_size,
                              hipStream_t stream) {
    const float* x = (const float*)d_in[0];
    const int* ei = (const int*)d_in[1];
    const int Nn = in_sizes[0] / 128;      // 50000
    const int E = in_sizes[1] / 2;         // 800000
    const int* src = ei;
    const int* dst = ei + E;

    char* ws = (char*)d_ws;
    size_t off = 0;
    auto alloc = [&](size_t bytes) -> char* {
        char* p = ws + off;
        off = (off + bytes + 255) & ~(size_t)255;
        return p;
    };
    int* cnt = (int*)alloc((size_t)Nn * 4);
    int* rank = (int*)alloc((size_t)E * 4);
    int* bsums = (int*)alloc(1024);
    float* dinv = (float*)alloc((size_t)Nn * 4);
    int* localRank = (int*)alloc((size_t)Nn * 4);
    int* hb = (int*)alloc((size_t)64 * 256 * 4);     // [64][nb], nb<=256
    int* perm = (int*)alloc((size_t)Nn * 4);
    int* pcnt = (int*)alloc((size_t)Nn * 4);
    int* iperm = (int*)alloc((size_t)Nn * 4);
    int* prowp2 = (int*)alloc((size_t)Nn * 4);
    int* rowo = (int*)alloc((size_t)Nn * 4);
    unsigned* edges2 = (unsigned*)alloc((size_t)(E + Nn + 64) * 4);
    unsigned short* T = (unsigned short*)alloc((size_t)Nn * 256 * 2);
    unsigned short* H = (unsigned short*)alloc((size_t)Nn * 256 * 2);
    unsigned short* Bx = (unsigned short*)alloc((size_t)Nn * 128 * 2);
    float* F = (float*)alloc((size_t)Nn * 4);
    unsigned short* Wts = (unsigned short*)alloc((size_t)400000 * 2);
    (void)ws_size;

    const int dims[9][2] = {{128,128},{128,192},{192,256},{256,256},{256,256},
                            {256,256},{256,192},{192,128},{128,1}};
    unsigned short* Wt[8];
    {
        size_t o = 0;
        for (int i = 0; i < 8; i++) { Wt[i] = Wts + o; o += (size_t)dims[i][0] * dims[i][1]; }
    }

    int nbN = (Nn + TPB - 1) / TPB;        // 196
    int nbE = (E + TPB - 1) / TPB;
    int nbEN = (E + Nn + TPB - 1) / TPB;

    // ---- graph prep: degree sort + direct sorted dense CSR build ----
    zinit_kernel<<<nbN, TPB, 0, stream>>>(cnt, Nn);
    count_kernel<<<nbE, TPB, 0, stream>>>(dst, cnt, rank, E);
    blockhist_kernel<<<nbN, TPB, 0, stream>>>(cnt, localRank, hb, dinv, Nn, nbN);
    sortscan_kernel<<<1, 256, 0, stream>>>(hb, nbN);
    scatter2_kernel<<<nbN, TPB, 0, stream>>>(cnt, localRank, hb, perm, pcnt, iperm,
                                             Nn, nbN);
    scan1_kernel<<<nbN, TPB, 0, stream>>>(pcnt, prowp2, bsums, Nn);
    scan3_kernel<<<nbN, TPB, 0, stream>>>(prowp2, bsums, Nn, nbN);
    rowo_kernel<<<nbN, TPB, 0, stream>>>(iperm, prowp2, rowo, Nn);
    fillself_kernel<<<nbEN, TPB, 0, stream>>>(src, dst, rank, dinv, rowo, cnt,
                                              edges2, E, Nn);

    // ---- weight transpose + input convert (single fused dispatch) ----
    WPtrs wp;
    for (int i = 0; i < 8; i++) wp.p[i] = (const float*)d_in[2 + 2 * i];
    int n4 = Nn * 32;
    wtcvt_kernel<<<(360448 + n4 + TPB - 1) / TPB, TPB, 0, stream>>>(wp, Wts, x, Bx, n4);

    auto gemm = [&](const unsigned short* A, int i, unsigned short* C, int K, int Nc,
                    int doBias, int doRelu, int outChunked) {
        const float* b = (const float*)d_in[3 + 2 * i];
        dim3 grid((Nn + 127) / 128, (Nc + 127) / 128);   // x: nodes, y: feats
        gemm_mfma_kernel<<<grid, 256, 0, stream>>>(A, Wt[i], b, C, Nn, K, Nc,
                                                   doBias, doRelu, outChunked);
    };
    int NG = (Nn + 31) / 32;               // 32 nodes per block
    auto agg = [&](const unsigned short* inb, unsigned short* outb, int w, int i,
                   int doBias, int doRelu, int outChunked) {
        int nch = w / 64;                                 // 64-feat chunks
        int Q = (nch == 4) ? 2 : (nch == 3) ? 8 : 4;      // nch*Q % 8 == 0
        int upx = nch * Q / 8;
        int ngPerUnit = (NG + Q - 1) / Q;
        int blocksPerXcd = upx * ngPerUnit;
        const float* b = (const float*)d_in[3 + 2 * i];
        agg_group_kernel<<<blocksPerXcd * 8, 256, 0, stream>>>(
            (const uint4*)inb, prowp2, pcnt, perm, edges2, b, (uint4*)outb,
            Q, upx, ngPerUnit, NG, Nn, w / 8, doBias, doRelu, outChunked);
    };

    // layout chain: GEMM in=row, out=chunked-64 (except G2: row); agg in=chunked,
    // out=row (except A0: chunked, feeds A1)
    gemm(Bx, 0, T, 128, 128, 0, 0, 1);      // G0: t = x@W0          -> T chunked
    agg(T, H, 128, 0, 1, 1, 1);             // A0: h1 = At+b0 relu   -> H chunked
    agg(H, T, 128, 1, 0, 0, 0);             // A1: u = A h1          -> T row
    gemm(T, 1, H, 128, 192, 1, 1, 1);       // G1: h2 = u@W1+b1 relu -> H chunked
    agg(H, T, 192, 2, 0, 0, 0);             // A2: u = A h2          -> T row
    gemm(T, 2, H, 192, 256, 1, 1, 0);       // G2: h3 = u@W2+b2 relu -> H row
    gemm(H, 3, T, 256, 256, 0, 0, 1);       // G3: t = h3@W3         -> T chunked
    agg(T, H, 256, 3, 1, 1, 0);             // A3: h4 = At+b3 relu   -> H row
    gemm(H, 4, T, 256, 256, 0, 0, 1);       // G4: t = h4@W4         -> T chunked
    agg(T, H, 256, 4, 1, 0, 0);             // A4: h5 = At+b4        -> H row
    gemm(H, 5, T, 256, 256, 0, 0, 1);       // G5: t = h5@W5         -> T chunked
    agg(T, H, 256, 5, 1, 1, 0);             // A5: h6 = At+b5 relu   -> H row
    gemm(H, 6, T, 256, 192, 0, 0, 1);       // G6: t = h6@W6         -> T chunked
    agg(T, H, 192, 6, 1, 1, 0);             // A6: h7 = At+b6 relu   -> H row
    gemm(H, 7, T, 192, 128, 0, 0, 1);       // G7: t = h7@W7         -> T chunked
    agg(T, H, 128, 7, 1, 1, 0);             // A7: h8 = At+b7 relu   -> H row
    gemv128_bf16_kernel<<<(Nn + 3) / 4, 256, 0, stream>>>(H, (const float*)d_in[2 + 16],
                                                          F, Nn);
    agg1_kernel<<<nbN, TPB, 0, stream>>>(F, prowp2, pcnt, perm, edges2,
                                         (const float*)d_in[3 + 16], (float*)d_out, Nn);
}

// Round 11
// 575.647 us; speedup vs baseline: 1.1044x; 1.0050x over previous
//
#include <hip/hip_runtime.h>

// ---------------------------------------------------------------------------
// GCN stack: 9 layers of  h = relu( Â (h W) + b ),  Â = D^-1/2 (A+I) D^-1/2
//   * Â(HW) == (ÂH)W  -> aggregate at width min(din,dout) per layer
//   * Â identical across layers -> CSR (self-loops folded) built once
// R25: GEMM K-loop was the T3 anti-pattern: barrier -> stage -> barrier
//     (vmcnt0 drain right after issue) -> compute = full HBM latency exposed
//     every K-step, zero overlap. Rewritten as minimal 2-phase pipeline
//     (guide 5.5-T3): Qb[2]/Pb[2] double buffer (64KB LDS), prologue stage,
//     then { stage(t+1, buf^1) -> compute(buf) -> one __syncthreads }: the
//     drain lands AFTER compute. Barriers halve. Plus XCD pairing for
//     Nc>=192 GEMMs: ids for (x,y=0/1) differ by 8 -> same XCD -> feat-tile
//     pair shares A in L2. Agg (R22 64-feat optimum) + prep unchanged.
// ---------------------------------------------------------------------------

#define TPB 256

using bf16x8 = __attribute__((ext_vector_type(8))) __bf16;
using f32x4  = __attribute__((ext_vector_type(4))) float;
using f32x2  = __attribute__((ext_vector_type(2))) float;

__device__ __forceinline__ unsigned bf16rne(float x) {
    unsigned u = __float_as_uint(x);
    return (u + 0x7fffu + ((u >> 16) & 1u)) >> 16;
}

__device__ __forceinline__ f32x2 bl2(unsigned u) {
    return (f32x2){__uint_as_float(u << 16), __uint_as_float(u & 0xffff0000u)};
}

// async global->LDS, 16B per lane. l is the WAVE-UNIFORM base; HW adds lane*16.
__device__ __forceinline__ void stage16(const unsigned short* g, unsigned short* l) {
#if __has_builtin(__builtin_amdgcn_global_load_lds)
    __builtin_amdgcn_global_load_lds((const __attribute__((address_space(1))) void*)g,
                                     (__attribute__((address_space(3))) void*)l, 16, 0, 0);
#else
    *(uint4*)((char*)l + (threadIdx.x & 63) * 16) = *(const uint4*)g;
#endif
}

// ---------------- graph prep kernels ----------------

__global__ void zinit_kernel(int* cnt, int n) {
    int i = blockIdx.x * blockDim.x + threadIdx.x;
    if (i < n) cnt[i] = 0;
}

// counts AND captures per-edge rank within its dst (order irrelevant)
__global__ void count_kernel(const int* __restrict__ dst, int* __restrict__ cnt,
                             int* __restrict__ rank, int E) {
    int e = blockIdx.x * blockDim.x + threadIdx.x;
    if (e < E) rank[e] = atomicAdd(&cnt[dst[e]], 1);
}

// ---- contention-free counting sort (degree bins 0..63) ----

__global__ void blockhist_kernel(const int* __restrict__ cnt, int* __restrict__ localRank,
                                 int* __restrict__ hb, float* __restrict__ dinv,
                                 int n, int nb) {
    __shared__ int h[64];
    int t = threadIdx.x;
    if (t < 64) h[t] = 0;
    __syncthreads();
    int i = blockIdx.x * TPB + t;
    if (i < n) {
        int c = cnt[i];
        dinv[i] = rsqrtf((float)(c + 1));
        int d = c; if (d > 63) d = 63;
        localRank[i] = atomicAdd(&h[d], 1);      // LDS atomic: fast
    }
    __syncthreads();
    if (t < 64) hb[t * nb + blockIdx.x] = h[t];
}

__global__ __launch_bounds__(256) void sortscan_kernel(int* __restrict__ hb, int nb) {
    __shared__ int sh[64 * 256];                  // 64 KB, nb <= 256
    __shared__ int tot[64], base[64];
    int t = threadIdx.x;
    int total = 64 * nb;
    for (int i = t; i < total; i += 256) sh[i] = hb[i];
    __syncthreads();
    if (t < 64) {
        int run = 0;
        for (int b = 0; b < nb; b++) {
            int v = sh[t * nb + b];
            sh[t * nb + b] = run;
            run += v;
        }
        tot[t] = run;
    }
    __syncthreads();
    if (t == 0) {
        int acc = 0;
        for (int b = 0; b < 64; b++) { base[b] = acc; acc += tot[b]; }
    }
    __syncthreads();
    for (int i = t; i < total; i += 256) hb[i] = sh[i] + base[i / nb];
}

__global__ void scatter2_kernel(const int* __restrict__ cnt,
                                const int* __restrict__ localRank, const int* __restrict__ hb,
                                int* __restrict__ perm, int* __restrict__ pcnt,
                                int* __restrict__ iperm, int n, int nb) {
    int i = blockIdx.x * TPB + threadIdx.x;
    if (i >= n) return;
    int c = cnt[i];
    int d = c; if (d > 63) d = 63;
    int pos = hb[d * nb + blockIdx.x] + localRank[i];
    perm[pos] = i;
    pcnt[pos] = c;
    iperm[i] = pos;
}

__global__ void scan1_kernel(const int* __restrict__ pcnt, int* __restrict__ prowp2,
                             int* __restrict__ bsums, int n) {
    __shared__ int sh[TPB];
    int t = threadIdx.x;
    int i = blockIdx.x * TPB + t;
    int v = (i < n) ? (pcnt[i] + 1) : 0;
    sh[t] = v;
    __syncthreads();
    for (int off = 1; off < TPB; off <<= 1) {
        int x = (t >= off) ? sh[t - off] : 0;
        __syncthreads();
        sh[t] += x;
        __syncthreads();
    }
    if (i < n) prowp2[i] = sh[t] - v;
    if (t == TPB - 1) bsums[blockIdx.x] = sh[t];
}

// scan3 with scan2 folded in: each block reduces bsums[0..blockIdx.x) itself.
__global__ void scan3_kernel(int* __restrict__ rowp, const int* __restrict__ bsums,
                             int n, int nb) {
    __shared__ int sh[TPB];
    int t = threadIdx.x;
    int v = (t < nb && t < (int)blockIdx.x) ? bsums[t] : 0;
    sh[t] = v;
    __syncthreads();
    for (int off = 1; off < TPB; off <<= 1) {
        int x = (t >= off) ? sh[t - off] : 0;
        __syncthreads();
        sh[t] += x;
        __syncthreads();
    }
    int offset = sh[TPB - 1];                     // sum of bsums[0..bid)
    int i = blockIdx.x * TPB + t;
    if (i < n) rowp[i] += offset;
}

// rowo[orig] = CSR row start of orig node (one N-sized gather pass, not E)
__global__ void rowo_kernel(const int* __restrict__ iperm, const int* __restrict__ prowp2,
                            int* __restrict__ rowo, int n) {
    int i = blockIdx.x * TPB + threadIdx.x;
    if (i < n) rowo[i] = prowp2[iperm[i]];
}

// real + self edges written DIRECTLY into sorted dense CSR, atomic-free.
// edge = u16 src | bf16(weight) << 16   (N=50000 < 65536)
__global__ void fillself_kernel(const int* __restrict__ src, const int* __restrict__ dst,
                                const int* __restrict__ rank,
                                const float* __restrict__ dinv,
                                const int* __restrict__ rowo,
                                const int* __restrict__ cnt,
                                unsigned* __restrict__ edges2, int E, int n) {
    int id = blockIdx.x * blockDim.x + threadIdx.x;
    if (id < E) {
        int s = src[id], d = dst[id];
        int pos = rowo[d] + rank[id];
        edges2[pos] = (unsigned)s | (bf16rne(dinv[s] * dinv[d]) << 16);
    } else if (id < E + n) {
        int i = id - E;
        float dv = dinv[i];
        edges2[rowo[i] + cnt[i]] = (unsigned)i | (bf16rne(dv * dv) << 16);
    }
}

// ---------------- weight / input prep (fused, one dispatch) ----------------

struct WPtrs { const float* p[8]; };

__global__ void wtcvt_kernel(WPtrs wp, unsigned short* __restrict__ Wts,
                             const float* __restrict__ xin,
                             unsigned short* __restrict__ Bx, int n4) {
    const int cum[9] = {0, 16384, 40960, 90112, 155648, 221184, 286720, 335872, 360448};
    const int Ns[8] = {128, 192, 256, 256, 256, 256, 192, 128};
    const int Ks[8] = {128, 128, 192, 256, 256, 256, 256, 192};
    int id = blockIdx.x * blockDim.x + threadIdx.x;
    if (id < 360448) {
        int L = 0;
#pragma unroll
        for (int t = 1; t < 8; t++) if (id >= cum[t]) L = t;
        int lid = id - cum[L];
        int N = Ns[L], K = Ks[L];
        int k = lid / N, n = lid - k * N;
        Wts[cum[L] + n * K + k] = (unsigned short)bf16rne(wp.p[L][lid]);
    } else {
        int i = id - 360448;
        if (i >= n4) return;
        float4 v = ((const float4*)xin)[i];
        uint2 o;
        o.x = bf16rne(v.x) | (bf16rne(v.y) << 16);
        o.y = bf16rne(v.z) | (bf16rne(v.w) << 16);
        ((uint2*)Bx)[i] = o;
    }
}

// ---------------- MFMA GEMM: 2-phase pipelined (stage t+1 || compute t) -----

// swz=1 (two feat-tiles): blockIdx.x = g*16 + r; bx = g*8 + (r&7), by = r>>3
// -> ids of (bx,0) and (bx,1) differ by 8 -> same XCD -> A-tile L2 reuse.
__global__ __launch_bounds__(256) void gemm_mfma_kernel(
    const unsigned short* __restrict__ A, const unsigned short* __restrict__ Wt,
    const float* __restrict__ bias, unsigned short* __restrict__ C,
    int M, int K, int Nc, int doBias, int doRelu, int outChunked,
    int nTilesX, int swz) {
    __shared__ unsigned short Qb[2][128 * 64];   // activations (nodes x K-chunk)
    __shared__ unsigned short Pb[2][128 * 64];   // weights (feats x K-chunk)
    int bx, by;
    if (swz) {
        int g = blockIdx.x >> 4, r = blockIdx.x & 15;
        bx = g * 8 + (r & 7); by = r >> 3;
        if (bx >= nTilesX) return;
    } else {
        bx = blockIdx.x; by = 0;
    }
    int tid = threadIdx.x;
    int l = tid & 63, w = tid >> 6;
    int node0 = bx * 128, feat0 = by * 128;

    f32x4 acc[4][4];
#pragma unroll
    for (int i = 0; i < 4; i++)
#pragma unroll
        for (int j = 0; j < 4; j++) acc[i][j] = (f32x4){0.f, 0.f, 0.f, 0.f};

    const unsigned short* gQ[4];
    const unsigned short* gP[4];
    int loff[4];
#pragma unroll
    for (int h = 0; h < 4; h++) {
        int slot = tid + h * 256;
        int r = slot >> 3, q = slot & 7;
        int qg = q ^ (r & 7);                  // global-side swizzle
        int nd = node0 + r; if (nd > M - 1) nd = M - 1;
        int ft = feat0 + r; if (ft > Nc - 1) ft = Nc - 1;
        gQ[h] = A + (size_t)nd * K + qg * 8;
        gP[h] = Wt + (size_t)ft * K + qg * 8;
        loff[h] = (w * 64 + h * 256) * 8;
    }

    int q4 = l >> 4, m16 = l & 15;
    int featHalf = w & 1, nodeHalf = w >> 1;
    int rP0 = featHalf * 64 + m16;
    int rQ0 = nodeHalf * 64 + m16;
    int sw = m16 & 7;
    int nk = K >> 6;

    // prologue: stage K-chunk 0 into buffer 0
#pragma unroll
    for (int h = 0; h < 4; h++) {
        stage16(gQ[h], Qb[0] + loff[h]);
        stage16(gP[h], Pb[0] + loff[h]);
    }
    __syncthreads();

    int cur = 0;
    for (int t = 0; t < nk; t++) {
        if (t + 1 < nk) {                      // issue next chunk BEFORE compute
            int k0 = (t + 1) << 6;
#pragma unroll
            for (int h = 0; h < 4; h++) {
                stage16(gQ[h] + k0, Qb[cur ^ 1] + loff[h]);
                stage16(gP[h] + k0, Pb[cur ^ 1] + loff[h]);
            }
        }
#pragma unroll
        for (int ko = 0; ko < 2; ko++) {
            bf16x8 pf[4], qf[4];
#pragma unroll
            for (int i = 0; i < 4; i++)
                pf[i] = *(const bf16x8*)(Pb[cur] + (rP0 + i * 16) * 64 + ((ko * 4 + q4) ^ sw) * 8);
#pragma unroll
            for (int j = 0; j < 4; j++)
                qf[j] = *(const bf16x8*)(Qb[cur] + (rQ0 + j * 16) * 64 + ((ko * 4 + q4) ^ sw) * 8);
#pragma unroll
            for (int i = 0; i < 4; i++)
#pragma unroll
                for (int j = 0; j < 4; j++)
                    acc[i][j] = __builtin_amdgcn_mfma_f32_16x16x32_bf16(pf[i], qf[j],
                                                                        acc[i][j], 0, 0, 0);
        }
        __syncthreads();                       // drain lands AFTER compute
        cur ^= 1;
    }

    // D layout: col(lane&15)=node, row(quad*4+reg)=feat -> 4 regs = 4 feats
#pragma unroll
    for (int i = 0; i < 4; i++) {
        int gf0 = feat0 + featHalf * 64 + i * 16 + q4 * 4;
        if (gf0 >= Nc) continue;
        float4 bv = make_float4(0.f, 0.f, 0.f, 0.f);
        if (doBias) bv = *(const float4*)(bias + gf0);
        size_t cb = outChunked ? ((size_t)(gf0 >> 6) * ((size_t)M * 64) + (gf0 & 63))
                               : (size_t)gf0;
#pragma unroll
        for (int j = 0; j < 4; j++) {
            int gn = node0 + nodeHalf * 64 + j * 16 + m16;
            if (gn >= M) continue;
            f32x4 v = acc[i][j];
            float x0 = v[0] + bv.x, x1 = v[1] + bv.y;
            float x2 = v[2] + bv.z, x3 = v[3] + bv.w;
            if (doRelu) {
                x0 = fmaxf(x0, 0.f); x1 = fmaxf(x1, 0.f);
                x2 = fmaxf(x2, 0.f); x3 = fmaxf(x3, 0.f);
            }
            uint2 o;
            o.x = bf16rne(x0) | (bf16rne(x1) << 16);
            o.y = bf16rne(x2) | (bf16rne(x3) << 16);
            size_t off = outChunked ? (cb + (size_t)gn * 64) : (cb + (size_t)gn * Nc);
            *(uint2*)(C + off) = o;
        }
    }
}

// out[m] = dot(A[m,0:128], w[0:128])  A bf16 row-major, one wave per row
__global__ void gemv128_bf16_kernel(const unsigned short* __restrict__ A,
                                    const float* __restrict__ w,
                                    float* __restrict__ out, int M) {
    int wid = (blockIdx.x * blockDim.x + threadIdx.x) >> 6;
    int lane = threadIdx.x & 63;
    if (wid >= M) return;
    const unsigned short* a = A + (size_t)wid * 128;
    float a0 = __uint_as_float((unsigned)a[lane] << 16);
    float a1 = __uint_as_float((unsigned)a[lane + 64] << 16);
    float s = a0 * w[lane] + a1 * w[lane + 64];
#pragma unroll
    for (int off = 32; off > 0; off >>= 1) s += __shfl_down(s, off);
    if (lane == 0) out[wid] = s;
}

// ---------------- aggregation: 64-feat chunks, 8-lane groups, pipelined -----

// R22 measured-best: 8 groups x 8 lanes per wave, one node per group,
// 32 nodes/block; each edge gathers 128B contiguous (8 lanes x uint4).
// Ping-pong A/B 4-edge sub-blocks: gathers for k+1 issued before FMA of k;
// edge words loaded 8 at a time. LPT order. Chunk->XCD slices (6.4MB).
__global__ __launch_bounds__(256) void agg_group_kernel(
    const uint4* __restrict__ in, const int* __restrict__ prowp2,
    const int* __restrict__ pcnt, const int* __restrict__ perm,
    const unsigned* __restrict__ edges2,
    const float* __restrict__ bias, uint4* __restrict__ out,
    int Q, int upx, int ngPerUnit, int NG, int n_nodes, int rowVec4,
    int doBias, int doRelu, int outChunked) {
    int xcd = blockIdx.x & 7;
    int slot = blockIdx.x >> 3;
    int u = slot / ngPerUnit;
    int ngIdx = slot - u * ngPerUnit;
    int unit = xcd * upx + u;
    int chunk = unit / Q;
    int q = unit - chunk * Q;
    int ng = ngIdx * Q + q;
    if (ng >= NG) return;
    ng = NG - 1 - ng;                          // heavy-degree blocks first (LPT)

    int wave = threadIdx.x >> 6;
    int lane = threadIdx.x & 63;
    int group = lane >> 3, fl = lane & 7;      // 8 groups x 8 lanes
    int gb = lane & ~7;
    int i = ng * 32 + wave * 8 + group;        // sorted index (32 nodes/block)
    if (i >= n_nodes) return;

    const uint4* sf = in + (size_t)chunk * n_nodes * 8 + fl;  // lane-fixed base
    int s0 = prowp2[i];
    int c = pcnt[i] + 1;
    int node = perm[i];
    const unsigned* ep = edges2 + s0;

    f32x2 acc[2][4];
#pragma unroll
    for (int k = 0; k < 2; k++)
#pragma unroll
        for (int m = 0; m < 4; m++) acc[k][m] = (f32x2){0.f, 0.f};

    // prologue: ew covers edges 0..7 (sub-blocks 0,1); issue block 0 gathers
    unsigned ew = (fl < c) ? ep[fl] : 0u;
    unsigned eA[4]; uint4 pA[4];
#pragma unroll
    for (int j = 0; j < 4; j++) eA[j] = (unsigned)__shfl((int)ew, gb + j);
#pragma unroll
    for (int j = 0; j < 4; j++) pA[j] = sf[(size_t)(eA[j] & 0xffffu) * 8];

    for (int base = 0; base < c; base += 8) {
        unsigned ewn = (base + 8 + fl < c) ? ep[base + 8 + fl] : 0u;  // blocks k+2,k+3
        unsigned eB[4]; uint4 pB[4];
#pragma unroll
        for (int j = 0; j < 4; j++) eB[j] = (unsigned)__shfl((int)ew, gb + 4 + j);
#pragma unroll
        for (int j = 0; j < 4; j++) pB[j] = sf[(size_t)(eB[j] & 0xffffu) * 8];
        // FMA block k (pA issued one half-iter ago)
#pragma unroll
        for (int j = 0; j < 4; j++) {
            float wgt = __uint_as_float(eA[j] & 0xffff0000u);         // inactive: +0.0
            f32x2 w2 = {wgt, wgt};
            int k = j & 1;
            acc[k][0] += w2 * bl2(pA[j].x);
            acc[k][1] += w2 * bl2(pA[j].y);
            acc[k][2] += w2 * bl2(pA[j].z);
            acc[k][3] += w2 * bl2(pA[j].w);
        }
        // issue block k+2 gathers
#pragma unroll
        for (int j = 0; j < 4; j++) eA[j] = (unsigned)__shfl((int)ewn, gb + j);
#pragma unroll
        for (int j = 0; j < 4; j++) pA[j] = sf[(size_t)(eA[j] & 0xffffu) * 8];
        // FMA block k+1
#pragma unroll
        for (int j = 0; j < 4; j++) {
            float wgt = __uint_as_float(eB[j] & 0xffff0000u);
            f32x2 w2 = {wgt, wgt};
            int k = j & 1;
            acc[k][0] += w2 * bl2(pB[j].x);
            acc[k][1] += w2 * bl2(pB[j].y);
            acc[k][2] += w2 * bl2(pB[j].z);
            acc[k][3] += w2 * bl2(pB[j].w);
        }
        ew = ewn;
    }
    f32x2 s[4];
#pragma unroll
    for (int m = 0; m < 4; m++) s[m] = acc[0][m] + acc[1][m];

    if (doBias) {
        const float* bp = bias + chunk * 64 + fl * 8;
        float4 b0 = *(const float4*)bp;
        float4 b1 = *(const float4*)(bp + 4);
        s[0] += (f32x2){b0.x, b0.y};
        s[1] += (f32x2){b0.z, b0.w};
        s[2] += (f32x2){b1.x, b1.y};
        s[3] += (f32x2){b1.z, b1.w};
    }
    if (doRelu) {
#pragma unroll
        for (int m = 0; m < 4; m++) {
            s[m][0] = fmaxf(s[m][0], 0.f);
            s[m][1] = fmaxf(s[m][1], 0.f);
        }
    }
    uint4 o;
    o.x = bf16rne(s[0][0]) | (bf16rne(s[0][1]) << 16);
    o.y = bf16rne(s[1][0]) | (bf16rne(s[1][1]) << 16);
    o.z = bf16rne(s[2][0]) | (bf16rne(s[2][1]) << 16);
    o.w = bf16rne(s[3][0]) | (bf16rne(s[3][1]) << 16);
    size_t oi = outChunked ? ((size_t)chunk * n_nodes * 8 + (size_t)node * 8 + fl)
                           : ((size_t)node * rowVec4 + chunk * 8 + fl);
    out[oi] = o;
}

// width-1 aggregation, fp32, sorted CSR: one thread per sorted node
__global__ void agg1_kernel(const float* __restrict__ in, const int* __restrict__ prowp2,
                            const int* __restrict__ pcnt, const int* __restrict__ perm,
                            const unsigned* __restrict__ edges2,
                            const float* __restrict__ bias, float* __restrict__ out,
                            int n_nodes) {
    int n = blockIdx.x * blockDim.x + threadIdx.x;
    if (n >= n_nodes) return;
    float acc = 0.f;
    int s0 = prowp2[n];
    int c = pcnt[n] + 1;
    for (int j = 0; j < c; j++) {
        unsigned e = edges2[s0 + j];
        acc += __uint_as_float(e & 0xffff0000u) * in[e & 0xffffu];
    }
    acc += bias[0];
    out[perm[n]] = acc;
}

// ---------------- host launcher ----------------

extern "C" void kernel_launch(void* const* d_in, const int* in_sizes, int n_in,
                              void* d_out, int out_size, void* d_ws, size_t ws_size,
                              hipStream_t stream) {
    const float* x = (const float*)d_in[0];
    const int* ei = (const int*)d_in[1];
    const int Nn = in_sizes[0] / 128;      // 50000
    const int E = in_sizes[1] / 2;         // 800000
    const int* src = ei;
    const int* dst = ei + E;

    char* ws = (char*)d_ws;
    size_t off = 0;
    auto alloc = [&](size_t bytes) -> char* {
        char* p = ws + off;
        off = (off + bytes + 255) & ~(size_t)255;
        return p;
    };
    int* cnt = (int*)alloc((size_t)Nn * 4);
    int* rank = (int*)alloc((size_t)E * 4);
    int* bsums = (int*)alloc(1024);
    float* dinv = (float*)alloc((size_t)Nn * 4);
    int* localRank = (int*)alloc((size_t)Nn * 4);
    int* hb = (int*)alloc((size_t)64 * 256 * 4);     // [64][nb], nb<=256
    int* perm = (int*)alloc((size_t)Nn * 4);
    int* pcnt = (int*)alloc((size_t)Nn * 4);
    int* iperm = (int*)alloc((size_t)Nn * 4);
    int* prowp2 = (int*)alloc((size_t)Nn * 4);
    int* rowo = (int*)alloc((size_t)Nn * 4);
    unsigned* edges2 = (unsigned*)alloc((size_t)(E + Nn + 64) * 4);
    unsigned short* T = (unsigned short*)alloc((size_t)Nn * 256 * 2);
    unsigned short* H = (unsigned short*)alloc((size_t)Nn * 256 * 2);
    unsigned short* Bx = (unsigned short*)alloc((size_t)Nn * 128 * 2);
    float* F = (float*)alloc((size_t)Nn * 4);
    unsigned short* Wts = (unsigned short*)alloc((size_t)400000 * 2);
    (void)ws_size;

    const int dims[9][2] = {{128,128},{128,192},{192,256},{256,256},{256,256},
                            {256,256},{256,192},{192,128},{128,1}};
    unsigned short* Wt[8];
    {
        size_t o = 0;
        for (int i = 0; i < 8; i++) { Wt[i] = Wts + o; o += (size_t)dims[i][0] * dims[i][1]; }
    }

    int nbN = (Nn + TPB - 1) / TPB;        // 196
    int nbE = (E + TPB - 1) / TPB;
    int nbEN = (E + Nn + TPB - 1) / TPB;

    // ---- graph prep: degree sort + direct sorted dense CSR build ----
    zinit_kernel<<<nbN, TPB, 0, stream>>>(cnt, Nn);
    count_kernel<<<nbE, TPB, 0, stream>>>(dst, cnt, rank, E);
    blockhist_kernel<<<nbN, TPB, 0, stream>>>(cnt, localRank, hb, dinv, Nn, nbN);
    sortscan_kernel<<<1, 256, 0, stream>>>(hb, nbN);
    scatter2_kernel<<<nbN, TPB, 0, stream>>>(cnt, localRank, hb, perm, pcnt, iperm,
                                             Nn, nbN);
    scan1_kernel<<<nbN, TPB, 0, stream>>>(pcnt, prowp2, bsums, Nn);
    scan3_kernel<<<nbN, TPB, 0, stream>>>(prowp2, bsums, Nn, nbN);
    rowo_kernel<<<nbN, TPB, 0, stream>>>(iperm, prowp2, rowo, Nn);
    fillself_kernel<<<nbEN, TPB, 0, stream>>>(src, dst, rank, dinv, rowo, cnt,
                                              edges2, E, Nn);

    // ---- weight transpose + input convert (single fused dispatch) ----
    WPtrs wp;
    for (int i = 0; i < 8; i++) wp.p[i] = (const float*)d_in[2 + 2 * i];
    int n4 = Nn * 32;
    wtcvt_kernel<<<(360448 + n4 + TPB - 1) / TPB, TPB, 0, stream>>>(wp, Wts, x, Bx, n4);

    int ntx = (Nn + 127) / 128;            // 391 node tiles
    auto gemm = [&](const unsigned short* A, int i, unsigned short* C, int K, int Nc,
                    int doBias, int doRelu, int outChunked) {
        const float* b = (const float*)d_in[3 + 2 * i];
        int nyt = (Nc + 127) / 128;
        if (nyt == 2) {
            int ng = (ntx + 7) / 8;        // XCD-paired swizzle, ids in groups of 16
            gemm_mfma_kernel<<<ng * 16, 256, 0, stream>>>(A, Wt[i], b, C, Nn, K, Nc,
                                                          doBias, doRelu, outChunked,
                                                          ntx, 1);
        } else {
            gemm_mfma_kernel<<<ntx, 256, 0, stream>>>(A, Wt[i], b, C, Nn, K, Nc,
                                                      doBias, doRelu, outChunked,
                                                      ntx, 0);
        }
    };
    int NG = (Nn + 31) / 32;               // 32 nodes per block
    auto agg = [&](const unsigned short* inb, unsigned short* outb, int w, int i,
                   int doBias, int doRelu, int outChunked) {
        int nch = w / 64;                                 // 64-feat chunks
        int Q = (nch == 4) ? 2 : (nch == 3) ? 8 : 4;      // nch*Q % 8 == 0
        int upx = nch * Q / 8;
        int ngPerUnit = (NG + Q - 1) / Q;
        int blocksPerXcd = upx * ngPerUnit;
        const float* b = (const float*)d_in[3 + 2 * i];
        agg_group_kernel<<<blocksPerXcd * 8, 256, 0, stream>>>(
            (const uint4*)inb, prowp2, pcnt, perm, edges2, b, (uint4*)outb,
            Q, upx, ngPerUnit, NG, Nn, w / 8, doBias, doRelu, outChunked);
    };

    // layout chain: GEMM in=row, out=chunked-64 (except G2: row); agg in=chunked,
    // out=row (except A0: chunked, feeds A1)
    gemm(Bx, 0, T, 128, 128, 0, 0, 1);      // G0: t = x@W0          -> T chunked
    agg(T, H, 128, 0, 1, 1, 1);             // A0: h1 = At+b0 relu   -> H chunked
    agg(H, T, 128, 1, 0, 0, 0);             // A1: u = A h1          -> T row
    gemm(T, 1, H, 128, 192, 1, 1, 1);       // G1: h2 = u@W1+b1 relu -> H chunked
    agg(H, T, 192, 2, 0, 0, 0);             // A2: u = A h2          -> T row
    gemm(T, 2, H, 192, 256, 1, 1, 0);       // G2: h3 = u@W2+b2 relu -> H row
    gemm(H, 3, T, 256, 256, 0, 0, 1);       // G3: t = h3@W3         -> T chunked
    agg(T, H, 256, 3, 1, 1, 0);             // A3: h4 = At+b3 relu   -> H row
    gemm(H, 4, T, 256, 256, 0, 0, 1);       // G4: t = h4@W4         -> T chunked
    agg(T, H, 256, 4, 1, 0, 0);             // A4: h5 = At+b4        -> H row
    gemm(H, 5, T, 256, 256, 0, 0, 1);       // G5: t = h5@W5         -> T chunked
    agg(T, H, 256, 5, 1, 1, 0);             // A5: h6 = At+b5 relu   -> H row
    gemm(H, 6, T, 256, 192, 0, 0, 1);       // G6: t = h6@W6         -> T c64
    agg(T, H, 192, 6, 1, 1, 0);             // A6: h7 = At+b6 relu   -> H row
    gemm(H, 7, T, 192, 128, 0, 0, 1);       // G7: t = h7@W7         -> T chunked
    agg(T, H, 128, 7, 1, 1, 0);             // A7: h8 = At+b7 relu   -> H row
    gemv128_bf16_kernel<<<(Nn + 3) / 4, 256, 0, stream>>>(H, (const float*)d_in[2 + 16],
                                                          F, Nn);
    agg1_kernel<<<nbN, TPB, 0, stream>>>(F, prowp2, pcnt, perm, edges2,
                                         (const float*)d_in[3 + 16], (float*)d_out, Nn);
}

// Round 12
// 556.601 us; speedup vs baseline: 1.1422x; 1.0342x over previous
//
#include <hip/hip_runtime.h>

// ---------------------------------------------------------------------------
// GCN stack: 9 layers of  h = relu( Â (h W) + b ),  Â = D^-1/2 (A+I) D^-1/2
//   * Â(HW) == (ÂH)W  -> aggregate at width min(din,dout) per layer
//   * Â identical across layers -> CSR (self-loops folded) built once
// R26: GEMM retiled for arithmetic intensity (R25 showed latency-hiding was
//     already covered by co-resident blocks): BM=128 x BN=Nc x BK=32,
//     512 thr (8 waves = 2 nodeHalf x 4 featQuad, NFR=Nc/64 frags each,
//     template<NFR>). Staged bytes/FLOP 33->87 FLOP/B; A read ONCE (BN
//     spans all feats -> A-HBM halves on Nc>=192 layers); LDS 32-48KB dbuf,
//     launch_bounds(512,4) caps VGPR<=128 -> 2 blocks/CU (16 waves).
//     2-phase stage-ahead loop kept (1 barrier/step). Agg = R22 64-feat
//     optimum; prep unchanged.
// ---------------------------------------------------------------------------

#define TPB 256

using bf16x8 = __attribute__((ext_vector_type(8))) __bf16;
using f32x4  = __attribute__((ext_vector_type(4))) float;
using f32x2  = __attribute__((ext_vector_type(2))) float;

__device__ __forceinline__ unsigned bf16rne(float x) {
    unsigned u = __float_as_uint(x);
    return (u + 0x7fffu + ((u >> 16) & 1u)) >> 16;
}

__device__ __forceinline__ f32x2 bl2(unsigned u) {
    return (f32x2){__uint_as_float(u << 16), __uint_as_float(u & 0xffff0000u)};
}

// async global->LDS, 16B per lane. l is the WAVE-UNIFORM base; HW adds lane*16.
__device__ __forceinline__ void stage16(const unsigned short* g, unsigned short* l) {
#if __has_builtin(__builtin_amdgcn_global_load_lds)
    __builtin_amdgcn_global_load_lds((const __attribute__((address_space(1))) void*)g,
                                     (__attribute__((address_space(3))) void*)l, 16, 0, 0);
#else
    *(uint4*)((char*)l + (threadIdx.x & 63) * 16) = *(const uint4*)g;
#endif
}

// ---------------- graph prep kernels ----------------

__global__ void zinit_kernel(int* cnt, int n) {
    int i = blockIdx.x * blockDim.x + threadIdx.x;
    if (i < n) cnt[i] = 0;
}

// counts AND captures per-edge rank within its dst (order irrelevant)
__global__ void count_kernel(const int* __restrict__ dst, int* __restrict__ cnt,
                             int* __restrict__ rank, int E) {
    int e = blockIdx.x * blockDim.x + threadIdx.x;
    if (e < E) rank[e] = atomicAdd(&cnt[dst[e]], 1);
}

// ---- contention-free counting sort (degree bins 0..63) ----

__global__ void blockhist_kernel(const int* __restrict__ cnt, int* __restrict__ localRank,
                                 int* __restrict__ hb, float* __restrict__ dinv,
                                 int n, int nb) {
    __shared__ int h[64];
    int t = threadIdx.x;
    if (t < 64) h[t] = 0;
    __syncthreads();
    int i = blockIdx.x * TPB + t;
    if (i < n) {
        int c = cnt[i];
        dinv[i] = rsqrtf((float)(c + 1));
        int d = c; if (d > 63) d = 63;
        localRank[i] = atomicAdd(&h[d], 1);      // LDS atomic: fast
    }
    __syncthreads();
    if (t < 64) hb[t * nb + blockIdx.x] = h[t];
}

__global__ __launch_bounds__(256) void sortscan_kernel(int* __restrict__ hb, int nb) {
    __shared__ int sh[64 * 256];                  // 64 KB, nb <= 256
    __shared__ int tot[64], base[64];
    int t = threadIdx.x;
    int total = 64 * nb;
    for (int i = t; i < total; i += 256) sh[i] = hb[i];
    __syncthreads();
    if (t < 64) {
        int run = 0;
        for (int b = 0; b < nb; b++) {
            int v = sh[t * nb + b];
            sh[t * nb + b] = run;
            run += v;
        }
        tot[t] = run;
    }
    __syncthreads();
    if (t == 0) {
        int acc = 0;
        for (int b = 0; b < 64; b++) { base[b] = acc; acc += tot[b]; }
    }
    __syncthreads();
    for (int i = t; i < total; i += 256) hb[i] = sh[i] + base[i / nb];
}

__global__ void scatter2_kernel(const int* __restrict__ cnt,
                                const int* __restrict__ localRank, const int* __restrict__ hb,
                                int* __restrict__ perm, int* __restrict__ pcnt,
                                int* __restrict__ iperm, int n, int nb) {
    int i = blockIdx.x * TPB + threadIdx.x;
    if (i >= n) return;
    int c = cnt[i];
    int d = c; if (d > 63) d = 63;
    int pos = hb[d * nb + blockIdx.x] + localRank[i];
    perm[pos] = i;
    pcnt[pos] = c;
    iperm[i] = pos;
}

__global__ void scan1_kernel(const int* __restrict__ pcnt, int* __restrict__ prowp2,
                             int* __restrict__ bsums, int n) {
    __shared__ int sh[TPB];
    int t = threadIdx.x;
    int i = blockIdx.x * TPB + t;
    int v = (i < n) ? (pcnt[i] + 1) : 0;
    sh[t] = v;
    __syncthreads();
    for (int off = 1; off < TPB; off <<= 1) {
        int x = (t >= off) ? sh[t - off] : 0;
        __syncthreads();
        sh[t] += x;
        __syncthreads();
    }
    if (i < n) prowp2[i] = sh[t] - v;
    if (t == TPB - 1) bsums[blockIdx.x] = sh[t];
}

// scan3 with scan2 folded in: each block reduces bsums[0..blockIdx.x) itself.
__global__ void scan3_kernel(int* __restrict__ rowp, const int* __restrict__ bsums,
                             int n, int nb) {
    __shared__ int sh[TPB];
    int t = threadIdx.x;
    int v = (t < nb && t < (int)blockIdx.x) ? bsums[t] : 0;
    sh[t] = v;
    __syncthreads();
    for (int off = 1; off < TPB; off <<= 1) {
        int x = (t >= off) ? sh[t - off] : 0;
        __syncthreads();
        sh[t] += x;
        __syncthreads();
    }
    int offset = sh[TPB - 1];                     // sum of bsums[0..bid)
    int i = blockIdx.x * TPB + t;
    if (i < n) rowp[i] += offset;
}

// rowo[orig] = CSR row start of orig node (one N-sized gather pass, not E)
__global__ void rowo_kernel(const int* __restrict__ iperm, const int* __restrict__ prowp2,
                            int* __restrict__ rowo, int n) {
    int i = blockIdx.x * TPB + threadIdx.x;
    if (i < n) rowo[i] = prowp2[iperm[i]];
}

// real + self edges written DIRECTLY into sorted dense CSR, atomic-free.
// edge = u16 src | bf16(weight) << 16   (N=50000 < 65536)
__global__ void fillself_kernel(const int* __restrict__ src, const int* __restrict__ dst,
                                const int* __restrict__ rank,
                                const float* __restrict__ dinv,
                                const int* __restrict__ rowo,
                                const int* __restrict__ cnt,
                                unsigned* __restrict__ edges2, int E, int n) {
    int id = blockIdx.x * blockDim.x + threadIdx.x;
    if (id < E) {
        int s = src[id], d = dst[id];
        int pos = rowo[d] + rank[id];
        edges2[pos] = (unsigned)s | (bf16rne(dinv[s] * dinv[d]) << 16);
    } else if (id < E + n) {
        int i = id - E;
        float dv = dinv[i];
        edges2[rowo[i] + cnt[i]] = (unsigned)i | (bf16rne(dv * dv) << 16);
    }
}

// ---------------- weight / input prep (fused, one dispatch) ----------------

struct WPtrs { const float* p[8]; };

__global__ void wtcvt_kernel(WPtrs wp, unsigned short* __restrict__ Wts,
                             const float* __restrict__ xin,
                             unsigned short* __restrict__ Bx, int n4) {
    const int cum[9] = {0, 16384, 40960, 90112, 155648, 221184, 286720, 335872, 360448};
    const int Ns[8] = {128, 192, 256, 256, 256, 256, 192, 128};
    const int Ks[8] = {128, 128, 192, 256, 256, 256, 256, 192};
    int id = blockIdx.x * blockDim.x + threadIdx.x;
    if (id < 360448) {
        int L = 0;
#pragma unroll
        for (int t = 1; t < 8; t++) if (id >= cum[t]) L = t;
        int lid = id - cum[L];
        int N = Ns[L], K = Ks[L];
        int k = lid / N, n = lid - k * N;
        Wts[cum[L] + n * K + k] = (unsigned short)bf16rne(wp.p[L][lid]);
    } else {
        int i = id - 360448;
        if (i >= n4) return;
        float4 v = ((const float4*)xin)[i];
        uint2 o;
        o.x = bf16rne(v.x) | (bf16rne(v.y) << 16);
        o.y = bf16rne(v.z) | (bf16rne(v.w) << 16);
        ((uint2*)Bx)[i] = o;
    }
}

// ---------------- MFMA GEMM: BM=128 x BN=Nc x BK=32, 8 waves, 2-phase -------

// NFR = Nc/64 feat-frags per wave. Waves: nodeHalf = w>>2, fq = w&3; wave
// covers 64 nodes x NFR*16 feats. A read ONCE per GEMM. Pre-swizzled global
// source (quad ^ (row&3)) -> linear LDS; read with the same XOR.
template<int NFR>
__global__ __launch_bounds__(512, 4) void gemm2_kernel(
    const unsigned short* __restrict__ A, const unsigned short* __restrict__ Wt,
    const float* __restrict__ bias, unsigned short* __restrict__ C,
    int M, int K, int doBias, int doRelu, int outChunked) {
    constexpr int Nc = NFR * 64;
    __shared__ unsigned short Qb[2][128 * 32];       // 8KB per buffer
    __shared__ unsigned short Pb[2][Nc * 32];        // Nc*64B per buffer
    int tid = threadIdx.x;
    int l = tid & 63, w = tid >> 6;                  // 8 waves
    int node0 = blockIdx.x * 128;

    f32x4 acc[4][NFR];
#pragma unroll
    for (int j = 0; j < 4; j++)
#pragma unroll
        for (int f = 0; f < NFR; f++) acc[j][f] = (f32x4){0.f, 0.f, 0.f, 0.f};

    // staging source pointers (pre-swizzled global quads)
    int rA = tid >> 2, qA = tid & 3;
    int nd = node0 + rA; if (nd > M - 1) nd = M - 1;
    const unsigned short* gA = A + (size_t)nd * K + (qA ^ (rA & 3)) * 8;
    const unsigned short* gW0 = Wt + (size_t)rA * K + (qA ^ (rA & 3)) * 8;
    const unsigned short* gW1 = gW0;                 // only used when NFR >= 3
    if (NFR >= 3) {
        int rW1 = 128 + rA;                          // rows 128..255 (< Nc used)
        gW1 = Wt + (size_t)rW1 * K + (qA ^ (rW1 & 3)) * 8;
    }
    int lB = w * 512;                                // wave-uniform LDS base (ushorts)

    int q4 = l >> 4, m16 = l & 15;
    int nodeHalf = w >> 2, fq = w & 3;
    int rQ0 = nodeHalf * 64 + m16;
    int rP0 = fq * (NFR * 16) + m16;
    int swq8 = (q4 ^ (m16 & 3)) * 8;
    int nk = K >> 5;

    // prologue: stage K-chunk 0 into buffer 0
    {
        stage16(gA, Qb[0] + lB);
        stage16(gW0, Pb[0] + lB);
        if constexpr (NFR == 4) stage16(gW1, Pb[0] + 4096 + lB);
        else if constexpr (NFR == 3) { if (w < 4) stage16(gW1, Pb[0] + 4096 + lB); }
    }
    __syncthreads();

    int cur = 0;
    for (int t = 0; t < nk; t++) {
        if (t + 1 < nk) {                            // stage next BEFORE compute
            int k0 = (t + 1) << 5;
            stage16(gA + k0, Qb[cur ^ 1] + lB);
            stage16(gW0 + k0, Pb[cur ^ 1] + lB);
            if constexpr (NFR == 4) stage16(gW1 + k0, Pb[cur ^ 1] + 4096 + lB);
            else if constexpr (NFR == 3) { if (w < 4) stage16(gW1 + k0, Pb[cur ^ 1] + 4096 + lB); }
        }
        bf16x8 qf[4], pf[NFR];
#pragma unroll
        for (int j = 0; j < 4; j++)
            qf[j] = *(const bf16x8*)(Qb[cur] + (rQ0 + j * 16) * 32 + swq8);
#pragma unroll
        for (int f = 0; f < NFR; f++)
            pf[f] = *(const bf16x8*)(Pb[cur] + (rP0 + f * 16) * 32 + swq8);
#pragma unroll
        for (int j = 0; j < 4; j++)
#pragma unroll
            for (int f = 0; f < NFR; f++)
                acc[j][f] = __builtin_amdgcn_mfma_f32_16x16x32_bf16(pf[f], qf[j],
                                                                    acc[j][f], 0, 0, 0);
        __syncthreads();                             // drain lands AFTER compute
        cur ^= 1;
    }

    // D layout: col(lane&15)=node, row(quad*4+reg)=feat
#pragma unroll
    for (int f = 0; f < NFR; f++) {
        int gf0 = fq * (NFR * 16) + f * 16 + q4 * 4;
        float4 bv = make_float4(0.f, 0.f, 0.f, 0.f);
        if (doBias) bv = *(const float4*)(bias + gf0);
        size_t cb = outChunked ? ((size_t)(gf0 >> 6) * ((size_t)M * 64) + (gf0 & 63))
                               : (size_t)gf0;
#pragma unroll
        for (int j = 0; j < 4; j++) {
            int gn = node0 + nodeHalf * 64 + j * 16 + m16;
            if (gn >= M) continue;
            f32x4 v = acc[j][f];
            float x0 = v[0] + bv.x, x1 = v[1] + bv.y;
            float x2 = v[2] + bv.z, x3 = v[3] + bv.w;
            if (doRelu) {
                x0 = fmaxf(x0, 0.f); x1 = fmaxf(x1, 0.f);
                x2 = fmaxf(x2, 0.f); x3 = fmaxf(x3, 0.f);
            }
            uint2 o;
            o.x = bf16rne(x0) | (bf16rne(x1) << 16);
            o.y = bf16rne(x2) | (bf16rne(x3) << 16);
            size_t off = outChunked ? (cb + (size_t)gn * 64) : (cb + (size_t)gn * Nc);
            *(uint2*)(C + off) = o;
        }
    }
}

// out[m] = dot(A[m,0:128], w[0:128])  A bf16 row-major, one wave per row
__global__ void gemv128_bf16_kernel(const unsigned short* __restrict__ A,
                                    const float* __restrict__ w,
                                    float* __restrict__ out, int M) {
    int wid = (blockIdx.x * blockDim.x + threadIdx.x) >> 6;
    int lane = threadIdx.x & 63;
    if (wid >= M) return;
    const unsigned short* a = A + (size_t)wid * 128;
    float a0 = __uint_as_float((unsigned)a[lane] << 16);
    float a1 = __uint_as_float((unsigned)a[lane + 64] << 16);
    float s = a0 * w[lane] + a1 * w[lane + 64];
#pragma unroll
    for (int off = 32; off > 0; off >>= 1) s += __shfl_down(s, off);
    if (lane == 0) out[wid] = s;
}

// ---------------- aggregation: 64-feat chunks, 8-lane groups, pipelined -----

// R22 measured-best: 8 groups x 8 lanes per wave, one node per group,
// 32 nodes/block; each edge gathers 128B contiguous (8 lanes x uint4).
// Ping-pong A/B 4-edge sub-blocks: gathers for k+1 issued before FMA of k;
// edge words loaded 8 at a time. LPT order. Chunk->XCD slices (6.4MB).
__global__ __launch_bounds__(256) void agg_group_kernel(
    const uint4* __restrict__ in, const int* __restrict__ prowp2,
    const int* __restrict__ pcnt, const int* __restrict__ perm,
    const unsigned* __restrict__ edges2,
    const float* __restrict__ bias, uint4* __restrict__ out,
    int Q, int upx, int ngPerUnit, int NG, int n_nodes, int rowVec4,
    int doBias, int doRelu, int outChunked) {
    int xcd = blockIdx.x & 7;
    int slot = blockIdx.x >> 3;
    int u = slot / ngPerUnit;
    int ngIdx = slot - u * ngPerUnit;
    int unit = xcd * upx + u;
    int chunk = unit / Q;
    int q = unit - chunk * Q;
    int ng = ngIdx * Q + q;
    if (ng >= NG) return;
    ng = NG - 1 - ng;                          // heavy-degree blocks first (LPT)

    int wave = threadIdx.x >> 6;
    int lane = threadIdx.x & 63;
    int group = lane >> 3, fl = lane & 7;      // 8 groups x 8 lanes
    int gb = lane & ~7;
    int i = ng * 32 + wave * 8 + group;        // sorted index (32 nodes/block)
    if (i >= n_nodes) return;

    const uint4* sf = in + (size_t)chunk * n_nodes * 8 + fl;  // lane-fixed base
    int s0 = prowp2[i];
    int c = pcnt[i] + 1;
    int node = perm[i];
    const unsigned* ep = edges2 + s0;

    f32x2 acc[2][4];
#pragma unroll
    for (int k = 0; k < 2; k++)
#pragma unroll
        for (int m = 0; m < 4; m++) acc[k][m] = (f32x2){0.f, 0.f};

    // prologue: ew covers edges 0..7 (sub-blocks 0,1); issue block 0 gathers
    unsigned ew = (fl < c) ? ep[fl] : 0u;
    unsigned eA[4]; uint4 pA[4];
#pragma unroll
    for (int j = 0; j < 4; j++) eA[j] = (unsigned)__shfl((int)ew, gb + j);
#pragma unroll
    for (int j = 0; j < 4; j++) pA[j] = sf[(size_t)(eA[j] & 0xffffu) * 8];

    for (int base = 0; base < c; base += 8) {
        unsigned ewn = (base + 8 + fl < c) ? ep[base + 8 + fl] : 0u;  // blocks k+2,k+3
        unsigned eB[4]; uint4 pB[4];
#pragma unroll
        for (int j = 0; j < 4; j++) eB[j] = (unsigned)__shfl((int)ew, gb + 4 + j);
#pragma unroll
        for (int j = 0; j < 4; j++) pB[j] = sf[(size_t)(eB[j] & 0xffffu) * 8];
        // FMA block k (pA issued one half-iter ago)
#pragma unroll
        for (int j = 0; j < 4; j++) {
            float wgt = __uint_as_float(eA[j] & 0xffff0000u);         // inactive: +0.0
            f32x2 w2 = {wgt, wgt};
            int k = j & 1;
            acc[k][0] += w2 * bl2(pA[j].x);
            acc[k][1] += w2 * bl2(pA[j].y);
            acc[k][2] += w2 * bl2(pA[j].z);
            acc[k][3] += w2 * bl2(pA[j].w);
        }
        // issue block k+2 gathers
#pragma unroll
        for (int j = 0; j < 4; j++) eA[j] = (unsigned)__shfl((int)ewn, gb + j);
#pragma unroll
        for (int j = 0; j < 4; j++) pA[j] = sf[(size_t)(eA[j] & 0xffffu) * 8];
        // FMA block k+1
#pragma unroll
        for (int j = 0; j < 4; j++) {
            float wgt = __uint_as_float(eB[j] & 0xffff0000u);
            f32x2 w2 = {wgt, wgt};
            int k = j & 1;
            acc[k][0] += w2 * bl2(pB[j].x);
            acc[k][1] += w2 * bl2(pB[j].y);
            acc[k][2] += w2 * bl2(pB[j].z);
            acc[k][3] += w2 * bl2(pB[j].w);
        }
        ew = ewn;
    }
    f32x2 s[4];
#pragma unroll
    for (int m = 0; m < 4; m++) s[m] = acc[0][m] + acc[1][m];

    if (doBias) {
        const float* bp = bias + chunk * 64 + fl * 8;
        float4 b0 = *(const float4*)bp;
        float4 b1 = *(const float4*)(bp + 4);
        s[0] += (f32x2){b0.x, b0.y};
        s[1] += (f32x2){b0.z, b0.w};
        s[2] += (f32x2){b1.x, b1.y};
        s[3] += (f32x2){b1.z, b1.w};
    }
    if (doRelu) {
#pragma unroll
        for (int m = 0; m < 4; m++) {
            s[m][0] = fmaxf(s[m][0], 0.f);
            s[m][1] = fmaxf(s[m][1], 0.f);
        }
    }
    uint4 o;
    o.x = bf16rne(s[0][0]) | (bf16rne(s[0][1]) << 16);
    o.y = bf16rne(s[1][0]) | (bf16rne(s[1][1]) << 16);
    o.z = bf16rne(s[2][0]) | (bf16rne(s[2][1]) << 16);
    o.w = bf16rne(s[3][0]) | (bf16rne(s[3][1]) << 16);
    size_t oi = outChunked ? ((size_t)chunk * n_nodes * 8 + (size_t)node * 8 + fl)
                           : ((size_t)node * rowVec4 + chunk * 8 + fl);
    out[oi] = o;
}

// width-1 aggregation, fp32, sorted CSR: one thread per sorted node
__global__ void agg1_kernel(const float* __restrict__ in, const int* __restrict__ prowp2,
                            const int* __restrict__ pcnt, const int* __restrict__ perm,
                            const unsigned* __restrict__ edges2,
                            const float* __restrict__ bias, float* __restrict__ out,
                            int n_nodes) {
    int n = blockIdx.x * blockDim.x + threadIdx.x;
    if (n >= n_nodes) return;
    float acc = 0.f;
    int s0 = prowp2[n];
    int c = pcnt[n] + 1;
    for (int j = 0; j < c; j++) {
        unsigned e = edges2[s0 + j];
        acc += __uint_as_float(e & 0xffff0000u) * in[e & 0xffffu];
    }
    acc += bias[0];
    out[perm[n]] = acc;
}

// ---------------- host launcher ----------------

extern "C" void kernel_launch(void* const* d_in, const int* in_sizes, int n_in,
                              void* d_out, int out_size, void* d_ws, size_t ws_size,
                              hipStream_t stream) {
    const float* x = (const float*)d_in[0];
    const int* ei = (const int*)d_in[1];
    const int Nn = in_sizes[0] / 128;      // 50000
    const int E = in_sizes[1] / 2;         // 800000
    const int* src = ei;
    const int* dst = ei + E;

    char* ws = (char*)d_ws;
    size_t off = 0;
    auto alloc = [&](size_t bytes) -> char* {
        char* p = ws + off;
        off = (off + bytes + 255) & ~(size_t)255;
        return p;
    };
    int* cnt = (int*)alloc((size_t)Nn * 4);
    int* rank = (int*)alloc((size_t)E * 4);
    int* bsums = (int*)alloc(1024);
    float* dinv = (float*)alloc((size_t)Nn * 4);
    int* localRank = (int*)alloc((size_t)Nn * 4);
    int* hb = (int*)alloc((size_t)64 * 256 * 4);     // [64][nb], nb<=256
    int* perm = (int*)alloc((size_t)Nn * 4);
    int* pcnt = (int*)alloc((size_t)Nn * 4);
    int* iperm = (int*)alloc((size_t)Nn * 4);
    int* prowp2 = (int*)alloc((size_t)Nn * 4);
    int* rowo = (int*)alloc((size_t)Nn * 4);
    unsigned* edges2 = (unsigned*)alloc((size_t)(E + Nn + 64) * 4);
    unsigned short* T = (unsigned short*)alloc((size_t)Nn * 256 * 2);
    unsigned short* H = (unsigned short*)alloc((size_t)Nn * 256 * 2);
    unsigned short* Bx = (unsigned short*)alloc((size_t)Nn * 128 * 2);
    float* F = (float*)alloc((size_t)Nn * 4);
    unsigned short* Wts = (unsigned short*)alloc((size_t)400000 * 2);
    (void)ws_size;

    const int dims[9][2] = {{128,128},{128,192},{192,256},{256,256},{256,256},
                            {256,256},{256,192},{192,128},{128,1}};
    unsigned short* Wt[8];
    {
        size_t o = 0;
        for (int i = 0; i < 8; i++) { Wt[i] = Wts + o; o += (size_t)dims[i][0] * dims[i][1]; }
    }

    int nbN = (Nn + TPB - 1) / TPB;        // 196
    int nbE = (E + TPB - 1) / TPB;
    int nbEN = (E + Nn + TPB - 1) / TPB;

    // ---- graph prep: degree sort + direct sorted dense CSR build ----
    zinit_kernel<<<nbN, TPB, 0, stream>>>(cnt, Nn);
    count_kernel<<<nbE, TPB, 0, stream>>>(dst, cnt, rank, E);
    blockhist_kernel<<<nbN, TPB, 0, stream>>>(cnt, localRank, hb, dinv, Nn, nbN);
    sortscan_kernel<<<1, 256, 0, stream>>>(hb, nbN);
    scatter2_kernel<<<nbN, TPB, 0, stream>>>(cnt, localRank, hb, perm, pcnt, iperm,
                                             Nn, nbN);
    scan1_kernel<<<nbN, TPB, 0, stream>>>(pcnt, prowp2, bsums, Nn);
    scan3_kernel<<<nbN, TPB, 0, stream>>>(prowp2, bsums, Nn, nbN);
    rowo_kernel<<<nbN, TPB, 0, stream>>>(iperm, prowp2, rowo, Nn);
    fillself_kernel<<<nbEN, TPB, 0, stream>>>(src, dst, rank, dinv, rowo, cnt,
                                              edges2, E, Nn);

    // ---- weight transpose + input convert (single fused dispatch) ----
    WPtrs wp;
    for (int i = 0; i < 8; i++) wp.p[i] = (const float*)d_in[2 + 2 * i];
    int n4 = Nn * 32;
    wtcvt_kernel<<<(360448 + n4 + TPB - 1) / TPB, TPB, 0, stream>>>(wp, Wts, x, Bx, n4);

    int ntx = (Nn + 127) / 128;            // 391 node tiles
    auto gemm = [&](const unsigned short* A, int i, unsigned short* C, int K, int Nc,
                    int doBias, int doRelu, int outChunked) {
        const float* b = (const float*)d_in[3 + 2 * i];
        if (Nc == 256)
            gemm2_kernel<4><<<ntx, 512, 0, stream>>>(A, Wt[i], b, C, Nn, K,
                                                     doBias, doRelu, outChunked);
        else if (Nc == 192)
            gemm2_kernel<3><<<ntx, 512, 0, stream>>>(A, Wt[i], b, C, Nn, K,
                                                     doBias, doRelu, outChunked);
        else
            gemm2_kernel<2><<<ntx, 512, 0, stream>>>(A, Wt[i], b, C, Nn, K,
                                                     doBias, doRelu, outChunked);
    };
    int NG = (Nn + 31) / 32;               // 32 nodes per block
    auto agg = [&](const unsigned short* inb, unsigned short* outb, int w, int i,
                   int doBias, int doRelu, int outChunked) {
        int nch = w / 64;                                 // 64-feat chunks
        int Q = (nch == 4) ? 2 : (nch == 3) ? 8 : 4;      // nch*Q % 8 == 0
        int upx = nch * Q / 8;
        int ngPerUnit = (NG + Q - 1) / Q;
        int blocksPerXcd = upx * ngPerUnit;
        const float* b = (const float*)d_in[3 + 2 * i];
        agg_group_kernel<<<blocksPerXcd * 8, 256, 0, stream>>>(
            (const uint4*)inb, prowp2, pcnt, perm, edges2, b, (uint4*)outb,
            Q, upx, ngPerUnit, NG, Nn, w / 8, doBias, doRelu, outChunked);
    };

    // layout chain: GEMM in=row, out=chunked-64 (except G2: row); agg in=chunked,
    // out=row (except A0: chunked, feeds A1)
    gemm(Bx, 0, T, 128, 128, 0, 0, 1);      // G0: t = x@W0          -> T chunked
    agg(T, H, 128, 0, 1, 1, 1);             // A0: h1 = At+b0 relu   -> H chunked
    agg(H, T, 128, 1, 0, 0, 0);             // A1: u = A h1          -> T row
    gemm(T, 1, H, 128, 192, 1, 1, 1);       // G1: h2 = u@W1+b1 relu -> H chunked
    agg(H, T, 192, 2, 0, 0, 0);             // A2: u = A h2          -> T row
    gemm(T, 2, H, 192, 256, 1, 1, 0);       // G2: h3 = u@W2+b2 relu -> H row
    gemm(H, 3, T, 256, 256, 0, 0, 1);       // G3: t = h3@W3         -> T chunked
    agg(T, H, 256, 3, 1, 1, 0);             // A3: h4 = At+b3 relu   -> H row
    gemm(H, 4, T, 256, 256, 0, 0, 1);       // G4: t = h4@W4         -> T chunked
    agg(T, H, 256, 4, 1, 0, 0);             // A4: h5 = At+b4        -> H row
    gemm(H, 5, T, 256, 256, 0, 0, 1);       // G5: t = h5@W5         -> T chunked
    agg(T, H, 256, 5, 1, 1, 0);             // A5: h6 = At+b5 relu   -> H row
    gemm(H, 6, T, 256, 192, 0, 0, 1);       // G6: t = h6@W6         -> T c64
    agg(T, H, 192, 6, 1, 1, 0);             // A6: h7 = At+b6 relu   -> H row
    gemm(H, 7, T, 192, 128, 0, 0, 1);       // G7: t = h7@W7         -> T chunked
    agg(T, H, 128, 7, 1, 1, 0);             // A7: h8 = At+b7 relu   -> H row
    gemv128_bf16_kernel<<<(Nn + 3) / 4, 256, 0, stream>>>(H, (const float*)d_in[2 + 16],
                                                          F, Nn);
    agg1_kernel<<<nbN, TPB, 0, stream>>>(F, prowp2, pcnt, perm, edges2,
                                         (const float*)d_in[3 + 16], (float*)d_out, Nn);
}